// Round 1
// baseline (1157.385 us; speedup 1.0000x reference)
//
#include <hip/hip_runtime.h>

// MHA fwd: B=4, S=1024, H=1024, NH=16, HD=64. All fp32.
// d_out = [out (4096*1024)] ++ [probs (64*1024*1024)]
// d_ws  = q,k,v,ctx each 4096*1024 floats (64 MB total)

#define BM 64
#define BN 64
#define BK 16
#define TM 4
#define TN 4
// 256 threads = (BM/TM)*(BN/TN)

// C[m,n] = sum_k A[m,k]*B[n,k] + bias[n]   (both A,B row-contiguous over k)
__global__ __launch_bounds__(256) void gemm_nt_kernel(
    const float* __restrict__ A, int lda, long sAo, long sAi,
    const float* __restrict__ B, int ldb, long sBo, long sBi,
    float* __restrict__ C, int ldc, long sCo, long sCi,
    int M, int N, int K, const float* __restrict__ bias)
{
    int z = blockIdx.z;
    long zo = z >> 4, zi = z & 15;
    A += zo * sAo + zi * sAi;
    B += zo * sBo + zi * sBi;
    C += zo * sCo + zi * sCi;

    __shared__ float As[BK][BM + 1];
    __shared__ float Bs[BK][BN + 1];

    int tid = threadIdx.x;
    int tx = tid & 15;   // 0..15 -> n group
    int ty = tid >> 4;   // 0..15 -> m group
    int lr = tid >> 4;   // loader row 0..15
    int lc = tid & 15;   // loader col (k) 0..15

    int m0 = blockIdx.y * BM;
    int n0 = blockIdx.x * BN;

    float acc[TM][TN] = {};

    for (int k0 = 0; k0 < K; k0 += BK) {
        #pragma unroll
        for (int p = 0; p < 4; ++p) {
            int m = lr + p * 16;
            As[lc][m] = A[(long)(m0 + m) * lda + k0 + lc];
        }
        #pragma unroll
        for (int p = 0; p < 4; ++p) {
            int n = lr + p * 16;
            Bs[lc][n] = B[(long)(n0 + n) * ldb + k0 + lc];
        }
        __syncthreads();
        #pragma unroll
        for (int kk = 0; kk < BK; ++kk) {
            float a[TM], b[TN];
            #pragma unroll
            for (int i = 0; i < TM; ++i) a[i] = As[kk][ty * TM + i];
            #pragma unroll
            for (int j = 0; j < TN; ++j) b[j] = Bs[kk][tx * TN + j];
            #pragma unroll
            for (int i = 0; i < TM; ++i)
                #pragma unroll
                for (int j = 0; j < TN; ++j)
                    acc[i][j] += a[i] * b[j];
        }
        __syncthreads();
    }

    #pragma unroll
    for (int i = 0; i < TM; ++i) {
        int m = m0 + ty * TM + i;
        #pragma unroll
        for (int j = 0; j < TN; ++j) {
            int n = n0 + tx * TN + j;
            float v = acc[i][j];
            if (bias) v += bias[n];
            C[(long)m * ldc + n] = v;
        }
    }
}

// C[m,n] = sum_k A[m,k]*B[k,n]
__global__ __launch_bounds__(256) void gemm_nn_kernel(
    const float* __restrict__ A, int lda, long sAo, long sAi,
    const float* __restrict__ B, int ldb, long sBo, long sBi,
    float* __restrict__ C, int ldc, long sCo, long sCi,
    int M, int N, int K, const float* __restrict__ bias)
{
    int z = blockIdx.z;
    long zo = z >> 4, zi = z & 15;
    A += zo * sAo + zi * sAi;
    B += zo * sBo + zi * sBi;
    C += zo * sCo + zi * sCi;

    __shared__ float As[BK][BM + 1];
    __shared__ float Bs[BK][BN + 1];

    int tid = threadIdx.x;
    int tx = tid & 15;
    int ty = tid >> 4;
    int lr = tid >> 4;
    int lc = tid & 15;
    int bn_col = tid & 63;   // B loader col 0..63
    int bn_row = tid >> 6;   // B loader row 0..3

    int m0 = blockIdx.y * BM;
    int n0 = blockIdx.x * BN;

    float acc[TM][TN] = {};

    for (int k0 = 0; k0 < K; k0 += BK) {
        #pragma unroll
        for (int p = 0; p < 4; ++p) {
            int m = lr + p * 16;
            As[lc][m] = A[(long)(m0 + m) * lda + k0 + lc];
        }
        #pragma unroll
        for (int p = 0; p < 4; ++p) {
            int kr = bn_row + p * 4;
            Bs[kr][bn_col] = B[(long)(k0 + kr) * ldb + n0 + bn_col];
        }
        __syncthreads();
        #pragma unroll
        for (int kk = 0; kk < BK; ++kk) {
            float a[TM], b[TN];
            #pragma unroll
            for (int i = 0; i < TM; ++i) a[i] = As[kk][ty * TM + i];
            #pragma unroll
            for (int j = 0; j < TN; ++j) b[j] = Bs[kk][tx * TN + j];
            #pragma unroll
            for (int i = 0; i < TM; ++i)
                #pragma unroll
                for (int j = 0; j < TN; ++j)
                    acc[i][j] += a[i] * b[j];
        }
        __syncthreads();
    }

    #pragma unroll
    for (int i = 0; i < TM; ++i) {
        int m = m0 + ty * TM + i;
        #pragma unroll
        for (int j = 0; j < TN; ++j) {
            int n = n0 + tx * TN + j;
            float v = acc[i][j];
            if (bias) v += bias[n];
            C[(long)m * ldc + n] = v;
        }
    }
}

// In-place: raw scores -> softmax(probs). Applies 1/sqrt(64) scale + additive mask.
__global__ __launch_bounds__(256) void softmax_kernel(
    float* __restrict__ probs, const float* __restrict__ mask)
{
    const int S = 1024;
    int row = blockIdx.x;            // 0..65535 = ((b*16+h)*1024+q)
    int b = row >> 14;               // / (16*1024)
    float* p = probs + (long)row * S;
    const float* mrow = mask + (long)b * S;
    int tid = threadIdx.x;

    float x[4];
    float mx = -1e30f;
    #pragma unroll
    for (int i = 0; i < 4; ++i) {
        int k = tid + i * 256;
        float s = p[k] * 0.125f + (1.0f - mrow[k]) * -10000.0f;
        x[i] = s;
        mx = fmaxf(mx, s);
    }
    __shared__ float red[256];
    red[tid] = mx;
    __syncthreads();
    for (int off = 128; off > 0; off >>= 1) {
        if (tid < off) red[tid] = fmaxf(red[tid], red[tid + off]);
        __syncthreads();
    }
    mx = red[0];
    __syncthreads();

    float sum = 0.f;
    #pragma unroll
    for (int i = 0; i < 4; ++i) {
        x[i] = __expf(x[i] - mx);
        sum += x[i];
    }
    red[tid] = sum;
    __syncthreads();
    for (int off = 128; off > 0; off >>= 1) {
        if (tid < off) red[tid] += red[tid + off];
        __syncthreads();
    }
    float inv = 1.0f / red[0];
    #pragma unroll
    for (int i = 0; i < 4; ++i) p[tid + i * 256] = x[i] * inv;
}

extern "C" void kernel_launch(void* const* d_in, const int* in_sizes, int n_in,
                              void* d_out, int out_size, void* d_ws, size_t ws_size,
                              hipStream_t stream) {
    const float* hs   = (const float*)d_in[0];  // [4,1024,1024]
    const float* mask = (const float*)d_in[1];  // [4,1024]
    const float* Wq   = (const float*)d_in[2];
    const float* bq   = (const float*)d_in[3];
    const float* Wk   = (const float*)d_in[4];
    const float* bk   = (const float*)d_in[5];
    const float* Wv   = (const float*)d_in[6];
    const float* bv   = (const float*)d_in[7];
    const float* Wo   = (const float*)d_in[8];
    const float* bo   = (const float*)d_in[9];

    const long MS = 4096;           // B*S
    const long HH = 1024;           // H
    const long SH = 1048576;        // S*H (per-batch stride in [B,S,H])
    const long SS = 1048576;        // S*S (per-(b,h) probs stride)

    float* out   = (float*)d_out;               // [4096,1024]
    float* probs = out + MS * HH;               // [64,1024,1024]
    float* q   = (float*)d_ws;
    float* k   = q + MS * HH;
    float* v   = k + MS * HH;
    float* ctx = v + MS * HH;

    dim3 blk(256);

    // 1) Q/K/V projections: [4096x1024] @ W^T + b  (kept in [B,S,H] layout)
    dim3 gproj(1024 / BN, 4096 / BM, 1);
    gemm_nt_kernel<<<gproj, blk, 0, stream>>>(hs, 1024, 0, 0, Wq, 1024, 0, 0,
                                              q, 1024, 0, 0, 4096, 1024, 1024, bq);
    gemm_nt_kernel<<<gproj, blk, 0, stream>>>(hs, 1024, 0, 0, Wk, 1024, 0, 0,
                                              k, 1024, 0, 0, 4096, 1024, 1024, bk);
    gemm_nt_kernel<<<gproj, blk, 0, stream>>>(hs, 1024, 0, 0, Wv, 1024, 0, 0,
                                              v, 1024, 0, 0, 4096, 1024, 1024, bv);

    // 2) raw scores = Q @ K^T per (b,h), written straight into probs region
    dim3 gsc(1024 / BN, 1024 / BM, 64);
    gemm_nt_kernel<<<gsc, blk, 0, stream>>>(q, 1024, SH, 64, k, 1024, SH, 64,
                                            probs, 1024, 16 * SS, SS,
                                            1024, 1024, 64, nullptr);

    // 3) softmax in-place (scale + mask folded in)
    softmax_kernel<<<65536, blk, 0, stream>>>(probs, mask);

    // 4) ctx = probs @ V per (b,h), stored in [B,S,H] layout
    dim3 gctx(64 / BN, 1024 / BM, 64);
    gemm_nn_kernel<<<gctx, blk, 0, stream>>>(probs, 1024, 16 * SS, SS,
                                             v, 1024, SH, 64,
                                             ctx, 1024, SH, 64,
                                             1024, 64, 1024, nullptr);

    // 5) out = ctx @ Wo^T + bo
    gemm_nt_kernel<<<gproj, blk, 0, stream>>>(ctx, 1024, 0, 0, Wo, 1024, 0, 0,
                                              out, 1024, 0, 0, 4096, 1024, 1024, bo);
}

// Round 2
// 327.690 us; speedup vs baseline: 3.5319x; 3.5319x over previous
//
#include <hip/hip_runtime.h>
#include <hip/hip_bf16.h>

// MHA fwd: B=4, S=1024, H=1024, NH=16, HD=64. fp32 in/out, bf16 MFMA inside.
// d_out = [out 4096x1024 f32] ++ [probs 64x1024x1024 f32]
// d_ws (64 MB): q_f32 16MB | k_f32 16MB | vt_b 8MB | ctx_b 8MB | hs_b 8MB | Wq/Wk/Wv/Wo_b 8MB

typedef __attribute__((ext_vector_type(8))) short short8;
typedef __attribute__((ext_vector_type(4))) float f32x4;
typedef __attribute__((ext_vector_type(4))) short short4v;

#define KDIM 1024

#define MFMA_BF16(a, b, c) __builtin_amdgcn_mfma_f32_16x16x32_bf16((a), (b), (c), 0, 0, 0)

__device__ __forceinline__ short f2bf(float x) {
    __hip_bfloat16 h = __float2bfloat16(x);
    return __builtin_bit_cast(short, h);
}
__device__ __forceinline__ float bf2f(short s) {
    __hip_bfloat16 h = __builtin_bit_cast(__hip_bfloat16, s);
    return __bfloat162float(h);
}

__device__ __forceinline__ void gload16(const void* g, void* lds) {
    __builtin_amdgcn_global_load_lds(
        (const __attribute__((address_space(1))) void*)g,
        (__attribute__((address_space(3))) void*)lds, 16, 0, 0);
}

// hi/lo split of 8 consecutive fp32 from LDS into two bf16 fragments
__device__ __forceinline__ void split8(const float* p, short8& hi, short8& lo) {
    f32x4 x0 = *(const f32x4*)p;
    f32x4 x1 = *(const f32x4*)(p + 4);
    float xs[8] = {x0[0], x0[1], x0[2], x0[3], x1[0], x1[1], x1[2], x1[3]};
    #pragma unroll
    for (int e = 0; e < 8; ++e) {
        short h = f2bf(xs[e]);
        float hf = bf2f(h);
        short l2 = f2bf(xs[e] - hf);
        hi[e] = h; lo[e] = l2;
    }
}

// ---------------- fp32 -> bf16 convert (8 elems/thread) ----------------
__global__ __launch_bounds__(256) void cvt_bf16_kernel(const float* __restrict__ src,
                                                       short* __restrict__ dst, int n8) {
    int i = blockIdx.x * 256 + threadIdx.x;
    if (i >= n8) return;
    const float4* s = (const float4*)src;
    float4 a = s[i * 2], b = s[i * 2 + 1];
    short8 o;
    o[0] = f2bf(a.x); o[1] = f2bf(a.y); o[2] = f2bf(a.z); o[3] = f2bf(a.w);
    o[4] = f2bf(b.x); o[5] = f2bf(b.y); o[6] = f2bf(b.z); o[7] = f2bf(b.w);
    *(short8*)(dst + (size_t)i * 8) = o;
}

// ---------------- bf16 NT GEMM: C[M=4096][1024] = A[4096][1024] @ B[1024][1024]^T + bias ----
// OMODE 0: fp32 row-major C. OMODE 1: bf16 vt layout [B][NH][64][1024] (for V).
template <int OMODE>
__global__ __launch_bounds__(256) void gemm_bt_kernel(
    const short* __restrict__ A, const short* __restrict__ B,
    float* __restrict__ Cf, short* __restrict__ Cb,
    const float* __restrict__ bias)
{
    __shared__ short As[128][32];   // 8 KB
    __shared__ short Bs[64][32];    // 4 KB
    int tid = threadIdx.x;
    int l = tid & 63, w = tid >> 6;
    int lr = l & 15, lg = l >> 4;
    int wm = w >> 1, wn = w & 1;
    int m0 = blockIdx.y * 128, n0 = blockIdx.x * 64;

    f32x4 acc[4][2] = {};

    const char* Ag = (const char*)A + (size_t)m0 * KDIM * 2;
    const char* Bg = (const char*)B + (size_t)n0 * KDIM * 2;
    char* AsB = (char*)As;
    char* BsB = (char*)Bs;
    int row_l = l >> 2;            // +q*16
    int col_l = (l & 3) * 16;      // byte offset within 64B row

    for (int k0 = 0; k0 < KDIM; k0 += 32) {
        __syncthreads();
        #pragma unroll
        for (int c = 0; c < 2; ++c) {
            int q = w * 2 + c;
            gload16(Ag + (size_t)(q * 16 + row_l) * (KDIM * 2) + k0 * 2 + col_l,
                    AsB + q * 1024);
        }
        gload16(Bg + (size_t)(w * 16 + row_l) * (KDIM * 2) + k0 * 2 + col_l,
                BsB + w * 1024);
        asm volatile("s_waitcnt vmcnt(0)" ::: "memory");
        __syncthreads();

        short8 a[4], b[2];
        #pragma unroll
        for (int i = 0; i < 4; ++i)
            a[i] = *(const short8*)(AsB + ((wm * 64 + i * 16 + lr) * 32 + lg * 8) * 2);
        #pragma unroll
        for (int j = 0; j < 2; ++j)
            b[j] = *(const short8*)(BsB + ((wn * 32 + j * 16 + lr) * 32 + lg * 8) * 2);
        #pragma unroll
        for (int i = 0; i < 4; ++i)
            #pragma unroll
            for (int j = 0; j < 2; ++j)
                acc[i][j] = MFMA_BF16(a[i], b[j], acc[i][j]);
    }

    #pragma unroll
    for (int i = 0; i < 4; ++i) {
        int m_base = m0 + wm * 64 + i * 16 + lg * 4;
        #pragma unroll
        for (int j = 0; j < 2; ++j) {
            int n = n0 + wn * 32 + j * 16 + lr;
            float bv = bias[n];
            if (OMODE == 0) {
                #pragma unroll
                for (int r = 0; r < 4; ++r)
                    Cf[(size_t)(m_base + r) * 1024 + n] = acc[i][j][r] + bv;
            } else {
                int b_ = m_base >> 10, s = m_base & 1023;
                int h = n >> 6, d = n & 63;
                short4v o;
                #pragma unroll
                for (int r = 0; r < 4; ++r) o[r] = f2bf(acc[i][j][r] + bv);
                *(short4v*)(Cb + ((size_t)((b_ * 16 + h) * 64 + d) * 1024 + s)) = o;
            }
        }
    }
}

// ---------------- scores = (Q @ K^T)/8 + maskadd, hi/lo split 3-pass MFMA ----------------
__global__ __launch_bounds__(256) void scores_kernel(
    const float* __restrict__ Q, const float* __restrict__ Kp,
    const float* __restrict__ mask, float* __restrict__ P)
{
    __shared__ float Qs[128][32];   // 16 KB
    __shared__ float Ks[128][32];   // 16 KB
    int tid = threadIdx.x, l = tid & 63, w = tid >> 6;
    int lr = l & 15, lg = l >> 4;
    int wm = w >> 1, wn = w & 1;
    int z = blockIdx.z;
    int b_ = z >> 4, h = z & 15;
    int m0 = blockIdx.y * 128, n0 = blockIdx.x * 128;

    const char* Qg = (const char*)(Q + (size_t)b_ * 1048576 + h * 64);
    const char* Kg = (const char*)(Kp + (size_t)b_ * 1048576 + h * 64);
    f32x4 acc[4][4] = {};
    int row_l = l >> 3, col_l = (l & 7) * 16;   // fp32 tile: 128B rows

    for (int k0 = 0; k0 < 64; k0 += 32) {
        __syncthreads();
        #pragma unroll
        for (int c = 0; c < 4; ++c) {
            int q = w * 4 + c;
            gload16(Qg + (size_t)(m0 + q * 8 + row_l) * 4096 + k0 * 4 + col_l,
                    (char*)Qs + q * 1024);
            gload16(Kg + (size_t)(n0 + q * 8 + row_l) * 4096 + k0 * 4 + col_l,
                    (char*)Ks + q * 1024);
        }
        asm volatile("s_waitcnt vmcnt(0)" ::: "memory");
        __syncthreads();

        short8 ah[4], al[4], bh[4], bl[4];
        #pragma unroll
        for (int i = 0; i < 4; ++i) split8(&Qs[wm * 64 + i * 16 + lr][lg * 8], ah[i], al[i]);
        #pragma unroll
        for (int j = 0; j < 4; ++j) split8(&Ks[wn * 64 + j * 16 + lr][lg * 8], bh[j], bl[j]);
        #pragma unroll
        for (int i = 0; i < 4; ++i)
            #pragma unroll
            for (int j = 0; j < 4; ++j) {
                acc[i][j] = MFMA_BF16(ah[i], bh[j], acc[i][j]);
                acc[i][j] = MFMA_BF16(ah[i], bl[j], acc[i][j]);
                acc[i][j] = MFMA_BF16(al[i], bh[j], acc[i][j]);
            }
    }

    float* Pz = P + (size_t)z * 1048576;
    const float* mrow = mask + b_ * 1024;
    #pragma unroll
    for (int i = 0; i < 4; ++i) {
        int m_base = m0 + wm * 64 + i * 16 + lg * 4;
        #pragma unroll
        for (int j = 0; j < 4; ++j) {
            int n = n0 + wn * 64 + j * 16 + lr;
            float madd = (1.0f - mrow[n]) * -10000.0f;
            #pragma unroll
            for (int r = 0; r < 4; ++r)
                Pz[(size_t)(m_base + r) * 1024 + n] = acc[i][j][r] * 0.125f + madd;
        }
    }
}

// ---------------- row softmax in-place over 1024 cols ----------------
__global__ __launch_bounds__(256) void softmax_kernel(float* __restrict__ P) {
    size_t row = blockIdx.x;
    float4* p = (float4*)(P + row * 1024);
    int tid = threadIdx.x;
    float4 x = p[tid];
    float mx = fmaxf(fmaxf(x.x, x.y), fmaxf(x.z, x.w));
    #pragma unroll
    for (int off = 32; off; off >>= 1) mx = fmaxf(mx, __shfl_xor(mx, off));
    __shared__ float wred[4], wred2[4];
    if ((tid & 63) == 0) wred[tid >> 6] = mx;
    __syncthreads();
    mx = fmaxf(fmaxf(wred[0], wred[1]), fmaxf(wred[2], wred[3]));
    x.x = __expf(x.x - mx); x.y = __expf(x.y - mx);
    x.z = __expf(x.z - mx); x.w = __expf(x.w - mx);
    float sm = x.x + x.y + x.z + x.w;
    #pragma unroll
    for (int off = 32; off; off >>= 1) sm += __shfl_xor(sm, off);
    if ((tid & 63) == 0) wred2[tid >> 6] = sm;
    __syncthreads();
    sm = (wred2[0] + wred2[1]) + (wred2[2] + wred2[3]);
    float inv = 1.0f / sm;
    x.x *= inv; x.y *= inv; x.z *= inv; x.w *= inv;
    p[tid] = x;
}

// ---------------- ctx = probs @ V  (probs fp32 -> bf16 on the fly, Vt pre-transposed) ------
__global__ __launch_bounds__(256) void pv_kernel(
    const float* __restrict__ P, const short* __restrict__ Vt,
    short* __restrict__ Ctx)
{
    __shared__ float Ps[128][32];   // 16 KB
    __shared__ short Vs[64][32];    // 4 KB
    int tid = threadIdx.x, l = tid & 63, w = tid >> 6;
    int lr = l & 15, lg = l >> 4;
    int z = blockIdx.y;
    int b_ = z >> 4, h = z & 15;
    int m0 = blockIdx.x * 128;

    const char* Pg = (const char*)(P + (size_t)z * 1048576);
    const char* Vg = (const char*)(Vt + (size_t)z * 65536);
    f32x4 acc[2][4] = {};
    int prow_l = l >> 3, pcol_l = (l & 7) * 16;   // fp32 tile
    int vrow_l = l >> 2, vcol_l = (l & 3) * 16;   // bf16 tile

    for (int k0 = 0; k0 < 1024; k0 += 32) {
        __syncthreads();
        #pragma unroll
        for (int c = 0; c < 4; ++c) {
            int q = w * 4 + c;
            gload16(Pg + (size_t)(m0 + q * 8 + prow_l) * 4096 + k0 * 4 + pcol_l,
                    (char*)Ps + q * 1024);
        }
        gload16(Vg + (size_t)(w * 16 + vrow_l) * 2048 + k0 * 2 + vcol_l,
                (char*)Vs + w * 1024);
        asm volatile("s_waitcnt vmcnt(0)" ::: "memory");
        __syncthreads();

        short8 a[2], b[4];
        #pragma unroll
        for (int i = 0; i < 2; ++i) {
            const float* p = &Ps[w * 32 + i * 16 + lr][lg * 8];
            f32x4 x0 = *(const f32x4*)p, x1 = *(const f32x4*)(p + 4);
            a[i][0] = f2bf(x0[0]); a[i][1] = f2bf(x0[1]);
            a[i][2] = f2bf(x0[2]); a[i][3] = f2bf(x0[3]);
            a[i][4] = f2bf(x1[0]); a[i][5] = f2bf(x1[1]);
            a[i][6] = f2bf(x1[2]); a[i][7] = f2bf(x1[3]);
        }
        #pragma unroll
        for (int j = 0; j < 4; ++j)
            b[j] = *(const short8*)((char*)Vs + ((j * 16 + lr) * 32 + lg * 8) * 2);
        #pragma unroll
        for (int i = 0; i < 2; ++i)
            #pragma unroll
            for (int j = 0; j < 4; ++j)
                acc[i][j] = MFMA_BF16(a[i], b[j], acc[i][j]);
    }

    #pragma unroll
    for (int i = 0; i < 2; ++i) {
        int m_base = m0 + w * 32 + i * 16 + lg * 4;
        #pragma unroll
        for (int j = 0; j < 4; ++j) {
            int n = j * 16 + lr;
            size_t base = ((size_t)(b_ * 1024) + m_base) * 1024 + h * 64 + n;
            #pragma unroll
            for (int r = 0; r < 4; ++r)
                Ctx[base + (size_t)r * 1024] = f2bf(acc[i][j][r]);
        }
    }
}

extern "C" void kernel_launch(void* const* d_in, const int* in_sizes, int n_in,
                              void* d_out, int out_size, void* d_ws, size_t ws_size,
                              hipStream_t stream) {
    const float* hs   = (const float*)d_in[0];
    const float* mask = (const float*)d_in[1];
    const float* Wq   = (const float*)d_in[2];
    const float* bq   = (const float*)d_in[3];
    const float* Wk   = (const float*)d_in[4];
    const float* bk   = (const float*)d_in[5];
    const float* Wv   = (const float*)d_in[6];
    const float* bv   = (const float*)d_in[7];
    const float* Wo   = (const float*)d_in[8];
    const float* bo   = (const float*)d_in[9];

    float* out   = (float*)d_out;
    float* probs = out + 4194304;

    char* ws = (char*)d_ws;
    float* q_f  = (float*)(ws);
    float* k_f  = (float*)(ws + (16u << 20));
    short* vt   = (short*)(ws + (32u << 20));
    short* ctxb = (short*)(ws + (40u << 20));
    short* hsb  = (short*)(ws + (48u << 20));
    short* wqb  = (short*)(ws + (56u << 20));
    short* wkb  = wqb + (1u << 20);
    short* wvb  = wkb + (1u << 20);
    short* wob  = wvb + (1u << 20);

    dim3 blk(256);

    // converts
    cvt_bf16_kernel<<<2048, blk, 0, stream>>>(hs, hsb, 524288);
    cvt_bf16_kernel<<<512, blk, 0, stream>>>(Wq, wqb, 131072);
    cvt_bf16_kernel<<<512, blk, 0, stream>>>(Wk, wkb, 131072);
    cvt_bf16_kernel<<<512, blk, 0, stream>>>(Wv, wvb, 131072);
    cvt_bf16_kernel<<<512, blk, 0, stream>>>(Wo, wob, 131072);

    // projections
    dim3 gproj(16, 32);
    gemm_bt_kernel<0><<<gproj, blk, 0, stream>>>(hsb, wqb, q_f, nullptr, bq);
    gemm_bt_kernel<0><<<gproj, blk, 0, stream>>>(hsb, wkb, k_f, nullptr, bk);
    gemm_bt_kernel<1><<<gproj, blk, 0, stream>>>(hsb, wvb, nullptr, vt, bv);

    // scores (raw -> probs region), mask+scale folded in
    scores_kernel<<<dim3(8, 8, 64), blk, 0, stream>>>(q_f, k_f, mask, probs);

    // softmax in place
    softmax_kernel<<<65536, blk, 0, stream>>>(probs);

    // ctx = probs @ V
    pv_kernel<<<dim3(8, 64), blk, 0, stream>>>(probs, vt, ctxb);

    // out = ctx @ Wo^T + bo
    gemm_bt_kernel<0><<<gproj, blk, 0, stream>>>(ctxb, wob, out, nullptr, bo);
}

// Round 3
// 284.228 us; speedup vs baseline: 4.0720x; 1.1529x over previous
//
#include <hip/hip_runtime.h>
#include <hip/hip_bf16.h>

// MHA fwd: B=4, S=1024, H=1024, NH=16, HD=64. fp32 in/out, bf16 MFMA inside.
// d_out = [out 4096x1024 f32] ++ [probs 64x1024x1024 f32]
// d_ws (64MB): qhi 8M | qlo 8M | khi 8M | klo 8M | vt 8M | ctxb 8M | hsb 8M | W*4 8M

typedef __attribute__((ext_vector_type(8))) short short8;
typedef __attribute__((ext_vector_type(4))) float f32x4;
typedef __attribute__((ext_vector_type(4))) short short4v;

#define KDIM 1024
#define LOG2E 1.44269504f
#define MFMA_BF16(a, b, c) __builtin_amdgcn_mfma_f32_16x16x32_bf16((a), (b), (c), 0, 0, 0)

__device__ __forceinline__ short f2bf(float x) {
    __hip_bfloat16 h = __float2bfloat16(x);
    return __builtin_bit_cast(short, h);
}
__device__ __forceinline__ float bf2f(short s) {
    __hip_bfloat16 h = __builtin_bit_cast(__hip_bfloat16, s);
    return __bfloat162float(h);
}

__device__ __forceinline__ void gload16(const void* g, void* lds) {
    __builtin_amdgcn_global_load_lds(
        (const __attribute__((address_space(1))) void*)g,
        (__attribute__((address_space(3))) void*)lds, 16, 0, 0);
}

// ---------------- fp32 -> bf16 convert (8 elems/thread) ----------------
__global__ __launch_bounds__(256) void cvt_bf16_kernel(const float* __restrict__ src,
                                                       short* __restrict__ dst, int n8) {
    int i = blockIdx.x * 256 + threadIdx.x;
    if (i >= n8) return;
    const float4* s = (const float4*)src;
    float4 a = s[i * 2], b = s[i * 2 + 1];
    short8 o;
    o[0] = f2bf(a.x); o[1] = f2bf(a.y); o[2] = f2bf(a.z); o[3] = f2bf(a.w);
    o[4] = f2bf(b.x); o[5] = f2bf(b.y); o[6] = f2bf(b.z); o[7] = f2bf(b.w);
    *(short8*)(dst + (size_t)i * 8) = o;
}

// ---------------- bf16 NT GEMM: C[4096][1024] = A @ B^T + bias ----------------
// OMODE 0: fp32 row-major C.
// OMODE 1: bf16 vt layout [B][NH][64][1024] (V).
// OMODE 2: hi/lo bf16 pair, row-major [4096][1024] each (Q or K), with postscale.
template <int OMODE>
__global__ __launch_bounds__(256) void gemm_bt_kernel(
    const short* __restrict__ A, const short* __restrict__ B,
    float* __restrict__ Cf, short* __restrict__ Cb, short* __restrict__ Cb2,
    const float* __restrict__ bias, float postscale)
{
    __shared__ short As[128][32];   // 8 KB
    __shared__ short Bs[64][32];    // 4 KB
    int tid = threadIdx.x;
    int l = tid & 63, w = tid >> 6;
    int lr = l & 15, lg = l >> 4;
    int wm = w >> 1, wn = w & 1;
    int m0 = blockIdx.y * 128, n0 = blockIdx.x * 64;

    f32x4 acc[4][2] = {};

    const char* Ag = (const char*)A + (size_t)m0 * KDIM * 2;
    const char* Bg = (const char*)B + (size_t)n0 * KDIM * 2;
    char* AsB = (char*)As;
    char* BsB = (char*)Bs;
    int row_l = l >> 2;
    int col_l = (l & 3) * 16;

    for (int k0 = 0; k0 < KDIM; k0 += 32) {
        __syncthreads();
        #pragma unroll
        for (int c = 0; c < 2; ++c) {
            int q = w * 2 + c;
            gload16(Ag + (size_t)(q * 16 + row_l) * (KDIM * 2) + k0 * 2 + col_l,
                    AsB + q * 1024);
        }
        gload16(Bg + (size_t)(w * 16 + row_l) * (KDIM * 2) + k0 * 2 + col_l,
                BsB + w * 1024);
        asm volatile("s_waitcnt vmcnt(0)" ::: "memory");
        __syncthreads();

        short8 a[4], b[2];
        #pragma unroll
        for (int i = 0; i < 4; ++i)
            a[i] = *(const short8*)(AsB + ((wm * 64 + i * 16 + lr) * 32 + lg * 8) * 2);
        #pragma unroll
        for (int j = 0; j < 2; ++j)
            b[j] = *(const short8*)(BsB + ((wn * 32 + j * 16 + lr) * 32 + lg * 8) * 2);
        #pragma unroll
        for (int i = 0; i < 4; ++i)
            #pragma unroll
            for (int j = 0; j < 2; ++j)
                acc[i][j] = MFMA_BF16(a[i], b[j], acc[i][j]);
    }

    #pragma unroll
    for (int i = 0; i < 4; ++i) {
        int m_base = m0 + wm * 64 + i * 16 + lg * 4;
        #pragma unroll
        for (int j = 0; j < 2; ++j) {
            int n = n0 + wn * 32 + j * 16 + lr;
            float bv = bias[n];
            if (OMODE == 0) {
                #pragma unroll
                for (int r = 0; r < 4; ++r)
                    Cf[(size_t)(m_base + r) * 1024 + n] = acc[i][j][r] + bv;
            } else if (OMODE == 1) {
                int b_ = m_base >> 10, s = m_base & 1023;
                int h = n >> 6, d = n & 63;
                short4v o;
                #pragma unroll
                for (int r = 0; r < 4; ++r) o[r] = f2bf(acc[i][j][r] + bv);
                *(short4v*)(Cb + ((size_t)((b_ * 16 + h) * 64 + d) * 1024 + s)) = o;
            } else {
                #pragma unroll
                for (int r = 0; r < 4; ++r) {
                    float v = (acc[i][j][r] + bv) * postscale;
                    short hh = f2bf(v);
                    short ll = f2bf(v - bf2f(hh));
                    Cb[(size_t)(m_base + r) * 1024 + n] = hh;
                    Cb2[(size_t)(m_base + r) * 1024 + n] = ll;
                }
            }
        }
    }
}

// -------- fused scores+softmax: probs[z][q][k] = softmax((Q K^T)/8 + maskadd) --------
// Block: 32 q-rows x 1024 k-cols, z = (b,h). Swapped mfma(K,Q): C[m=k][n=q].
// Q pre-scaled by 0.125 at projection; hi/lo 3-pass for exact f32 products.
__global__ __launch_bounds__(256) void attn_fused_kernel(
    const short* __restrict__ Qhi, const short* __restrict__ Qlo,
    const short* __restrict__ Khi, const short* __restrict__ Klo,
    const float* __restrict__ mask, float* __restrict__ P)
{
    constexpr int QHI_O = 0, QLO_O = 4096, KHI_O = 8192, KLO_O = 24576,
                  MADD_O = 40960, WRM_O = 45056, WRL_O = 45568;
    __shared__ __align__(16) char lds[46080];

    int tid = threadIdx.x;
    int l = tid & 63, w = tid >> 6;
    int c = l & 15, g = l >> 4;
    int z = blockIdx.y;
    int b = z >> 4, h = z & 15;
    int qb = blockIdx.x;

    // madd[k] = (1 - mask[b][k]) * -10000
    {
        const float4* mrow = (const float4*)(mask + b * 1024);
        float4 mm = mrow[tid];
        float4 md;
        md.x = (1.0f - mm.x) * -10000.0f;
        md.y = (1.0f - mm.y) * -10000.0f;
        md.z = (1.0f - mm.z) * -10000.0f;
        md.w = (1.0f - mm.w) * -10000.0f;
        *(float4*)(lds + MADD_O + tid * 16) = md;
    }

    // stage Q hi/lo: 32 rows x 128B, XOR-swizzled via pre-swizzled global source
    {
        int r_ = w * 8 + (l >> 3);
        int ul = (l & 7) ^ (r_ & 7);
        size_t gq = ((size_t)(b * 1024 + qb * 32 + r_)) * 1024 + h * 64 + ul * 8;
        gload16(Qhi + gq, lds + QHI_O + w * 1024);
        gload16(Qlo + gq, lds + QLO_O + w * 1024);
    }
    asm volatile("s_waitcnt vmcnt(0)" ::: "memory");
    __syncthreads();

    // Q fragments (B operand): row = qt*16 + c
    short8 bqh[2][2], bql[2][2];
    #pragma unroll
    for (int qt = 0; qt < 2; ++qt) {
        int row = qt * 16 + c;
        #pragma unroll
        for (int dt = 0; dt < 2; ++dt) {
            int u = (dt * 4 + g) ^ (row & 7);
            bqh[qt][dt] = *(const short8*)(lds + QHI_O + row * 128 + u * 16);
            bql[qt][dt] = *(const short8*)(lds + QLO_O + row * 128 + u * 16);
        }
    }

    f32x4 acc[8][2][2] = {};

    #pragma unroll
    for (int cc = 0; cc < 8; ++cc) {
        #pragma unroll
        for (int i = 0; i < 4; ++i) {
            int r_ = i * 32 + w * 8 + (l >> 3);
            int ul = (l & 7) ^ (r_ & 7);
            size_t gk = ((size_t)(b * 1024 + cc * 128 + r_)) * 1024 + h * 64 + ul * 8;
            gload16(Khi + gk, lds + KHI_O + i * 4096 + w * 1024);
            gload16(Klo + gk, lds + KLO_O + i * 4096 + w * 1024);
        }
        asm volatile("s_waitcnt vmcnt(0)" ::: "memory");
        __syncthreads();

        #pragma unroll
        for (int kt = 0; kt < 2; ++kt) {
            int row = w * 32 + kt * 16 + c;
            #pragma unroll
            for (int dt = 0; dt < 2; ++dt) {
                int u = (dt * 4 + g) ^ (row & 7);
                short8 ah = *(const short8*)(lds + KHI_O + row * 128 + u * 16);
                short8 al = *(const short8*)(lds + KLO_O + row * 128 + u * 16);
                #pragma unroll
                for (int qt = 0; qt < 2; ++qt) {
                    acc[cc][kt][qt] = MFMA_BF16(ah, bqh[qt][dt], acc[cc][kt][qt]);
                    acc[cc][kt][qt] = MFMA_BF16(ah, bql[qt][dt], acc[cc][kt][qt]);
                    acc[cc][kt][qt] = MFMA_BF16(al, bqh[qt][dt], acc[cc][kt][qt]);
                }
            }
        }
        __syncthreads();
    }

    // ---- softmax epilogue: s = acc + madd; m,l over k; p = exp(s-m)/l ----
    float mx[2] = {-3.0e38f, -3.0e38f};
    #pragma unroll
    for (int cc = 0; cc < 8; ++cc)
        #pragma unroll
        for (int kt = 0; kt < 2; ++kt) {
            f32x4 md = *(const f32x4*)(lds + MADD_O + (cc * 128 + w * 32 + kt * 16 + g * 4) * 4);
            #pragma unroll
            for (int qt = 0; qt < 2; ++qt) {
                f32x4 v = acc[cc][kt][qt] + md;
                acc[cc][kt][qt] = v;
                mx[qt] = fmaxf(mx[qt], fmaxf(fmaxf(v[0], v[1]), fmaxf(v[2], v[3])));
            }
        }
    #pragma unroll
    for (int qt = 0; qt < 2; ++qt) {
        mx[qt] = fmaxf(mx[qt], __shfl_xor(mx[qt], 16));
        mx[qt] = fmaxf(mx[qt], __shfl_xor(mx[qt], 32));
    }
    float* wrm = (float*)(lds + WRM_O);
    float* wrl = (float*)(lds + WRL_O);
    if (g == 0) { wrm[w * 32 + c] = mx[0]; wrm[w * 32 + 16 + c] = mx[1]; }
    __syncthreads();
    float mfin[2];
    mfin[0] = fmaxf(fmaxf(wrm[c], wrm[32 + c]), fmaxf(wrm[64 + c], wrm[96 + c]));
    mfin[1] = fmaxf(fmaxf(wrm[16 + c], wrm[48 + c]), fmaxf(wrm[80 + c], wrm[112 + c]));

    float sum[2] = {0.0f, 0.0f};
    #pragma unroll
    for (int cc = 0; cc < 8; ++cc)
        #pragma unroll
        for (int kt = 0; kt < 2; ++kt)
            #pragma unroll
            for (int qt = 0; qt < 2; ++qt) {
                f32x4 v = acc[cc][kt][qt];
                v[0] = exp2f((v[0] - mfin[qt]) * LOG2E);
                v[1] = exp2f((v[1] - mfin[qt]) * LOG2E);
                v[2] = exp2f((v[2] - mfin[qt]) * LOG2E);
                v[3] = exp2f((v[3] - mfin[qt]) * LOG2E);
                acc[cc][kt][qt] = v;
                sum[qt] += (v[0] + v[1]) + (v[2] + v[3]);
            }
    #pragma unroll
    for (int qt = 0; qt < 2; ++qt) {
        sum[qt] += __shfl_xor(sum[qt], 16);
        sum[qt] += __shfl_xor(sum[qt], 32);
    }
    if (g == 0) { wrl[w * 32 + c] = sum[0]; wrl[w * 32 + 16 + c] = sum[1]; }
    __syncthreads();
    float inv[2];
    inv[0] = 1.0f / ((wrl[c] + wrl[32 + c]) + (wrl[64 + c] + wrl[96 + c]));
    inv[1] = 1.0f / ((wrl[16 + c] + wrl[48 + c]) + (wrl[80 + c] + wrl[112 + c]));

    float* Pz = P + ((size_t)z << 20);
    #pragma unroll
    for (int cc = 0; cc < 8; ++cc)
        #pragma unroll
        for (int kt = 0; kt < 2; ++kt)
            #pragma unroll
            for (int qt = 0; qt < 2; ++qt) {
                f32x4 v = acc[cc][kt][qt];
                v[0] *= inv[qt]; v[1] *= inv[qt]; v[2] *= inv[qt]; v[3] *= inv[qt];
                int q = qb * 32 + qt * 16 + c;
                int k = cc * 128 + w * 32 + kt * 16 + g * 4;
                *(f32x4*)(Pz + (size_t)q * 1024 + k) = v;
            }
}

// ---------------- ctx = probs @ V (probs fp32 -> bf16 on the fly) ----------------
__global__ __launch_bounds__(256) void pv_kernel(
    const float* __restrict__ P, const short* __restrict__ Vt,
    short* __restrict__ Ctx)
{
    __shared__ float Ps[128][32];   // 16 KB
    __shared__ short Vs[64][32];    // 4 KB
    int tid = threadIdx.x, l = tid & 63, w = tid >> 6;
    int lr = l & 15, lg = l >> 4;
    int z = blockIdx.y;
    int b_ = z >> 4, h = z & 15;
    int m0 = blockIdx.x * 128;

    const char* Pg = (const char*)(P + (size_t)z * 1048576);
    const char* Vg = (const char*)(Vt + (size_t)z * 65536);
    f32x4 acc[2][4] = {};
    int prow_l = l >> 3, pcol_l = (l & 7) * 16;
    int vrow_l = l >> 2, vcol_l = (l & 3) * 16;

    for (int k0 = 0; k0 < 1024; k0 += 32) {
        __syncthreads();
        #pragma unroll
        for (int c = 0; c < 4; ++c) {
            int q = w * 4 + c;
            gload16(Pg + (size_t)(m0 + q * 8 + prow_l) * 4096 + k0 * 4 + pcol_l,
                    (char*)Ps + q * 1024);
        }
        gload16(Vg + (size_t)(w * 16 + vrow_l) * 2048 + k0 * 2 + vcol_l,
                (char*)Vs + w * 1024);
        asm volatile("s_waitcnt vmcnt(0)" ::: "memory");
        __syncthreads();

        short8 a[2], b[4];
        #pragma unroll
        for (int i = 0; i < 2; ++i) {
            const float* p = &Ps[w * 32 + i * 16 + lr][lg * 8];
            f32x4 x0 = *(const f32x4*)p, x1 = *(const f32x4*)(p + 4);
            a[i][0] = f2bf(x0[0]); a[i][1] = f2bf(x0[1]);
            a[i][2] = f2bf(x0[2]); a[i][3] = f2bf(x0[3]);
            a[i][4] = f2bf(x1[0]); a[i][5] = f2bf(x1[1]);
            a[i][6] = f2bf(x1[2]); a[i][7] = f2bf(x1[3]);
        }
        #pragma unroll
        for (int j = 0; j < 4; ++j)
            b[j] = *(const short8*)((char*)Vs + ((j * 16 + lr) * 32 + lg * 8) * 2);
        #pragma unroll
        for (int i = 0; i < 2; ++i)
            #pragma unroll
            for (int j = 0; j < 4; ++j)
                acc[i][j] = MFMA_BF16(a[i], b[j], acc[i][j]);
    }

    #pragma unroll
    for (int i = 0; i < 2; ++i) {
        int m_base = m0 + w * 32 + i * 16 + lg * 4;
        #pragma unroll
        for (int j = 0; j < 4; ++j) {
            int n = j * 16 + lr;
            size_t base = ((size_t)(b_ * 1024) + m_base) * 1024 + h * 64 + n;
            #pragma unroll
            for (int r = 0; r < 4; ++r)
                Ctx[base + (size_t)r * 1024] = f2bf(acc[i][j][r]);
        }
    }
}

extern "C" void kernel_launch(void* const* d_in, const int* in_sizes, int n_in,
                              void* d_out, int out_size, void* d_ws, size_t ws_size,
                              hipStream_t stream) {
    const float* hs   = (const float*)d_in[0];
    const float* mask = (const float*)d_in[1];
    const float* Wq   = (const float*)d_in[2];
    const float* bq   = (const float*)d_in[3];
    const float* Wk   = (const float*)d_in[4];
    const float* bk   = (const float*)d_in[5];
    const float* Wv   = (const float*)d_in[6];
    const float* bv   = (const float*)d_in[7];
    const float* Wo   = (const float*)d_in[8];
    const float* bo   = (const float*)d_in[9];

    float* out   = (float*)d_out;
    float* probs = out + 4194304;

    char* ws = (char*)d_ws;
    short* qhi  = (short*)(ws);
    short* qlo  = (short*)(ws + (8u << 20));
    short* khi  = (short*)(ws + (16u << 20));
    short* klo  = (short*)(ws + (24u << 20));
    short* vt   = (short*)(ws + (32u << 20));
    short* ctxb = (short*)(ws + (40u << 20));
    short* hsb  = (short*)(ws + (48u << 20));
    short* wqb  = (short*)(ws + (56u << 20));
    short* wkb  = wqb + (1u << 20);
    short* wvb  = wkb + (1u << 20);
    short* wob  = wvb + (1u << 20);

    dim3 blk(256);

    cvt_bf16_kernel<<<2048, blk, 0, stream>>>(hs, hsb, 524288);
    cvt_bf16_kernel<<<512, blk, 0, stream>>>(Wq, wqb, 131072);
    cvt_bf16_kernel<<<512, blk, 0, stream>>>(Wk, wkb, 131072);
    cvt_bf16_kernel<<<512, blk, 0, stream>>>(Wv, wvb, 131072);
    cvt_bf16_kernel<<<512, blk, 0, stream>>>(Wo, wob, 131072);

    dim3 gproj(16, 32);
    // Q: 0.125 scale folded in; hi/lo pair outputs
    gemm_bt_kernel<2><<<gproj, blk, 0, stream>>>(hsb, wqb, nullptr, qhi, qlo, bq, 0.125f);
    gemm_bt_kernel<2><<<gproj, blk, 0, stream>>>(hsb, wkb, nullptr, khi, klo, bk, 1.0f);
    gemm_bt_kernel<1><<<gproj, blk, 0, stream>>>(hsb, wvb, nullptr, vt, nullptr, bv, 1.0f);

    // fused scores+softmax -> probs (written once, normalized)
    attn_fused_kernel<<<dim3(32, 64), blk, 0, stream>>>(qhi, qlo, khi, klo, mask, probs);

    // ctx = probs @ V
    pv_kernel<<<dim3(8, 64), blk, 0, stream>>>(probs, vt, ctxb);

    // out = ctx @ Wo^T + bo
    gemm_bt_kernel<0><<<gproj, blk, 0, stream>>>(ctxb, wob, out, nullptr, nullptr, bo, 1.0f);
}

// Round 4
// 273.514 us; speedup vs baseline: 4.2315x; 1.0392x over previous
//
#include <hip/hip_runtime.h>
#include <hip/hip_bf16.h>

// MHA fwd: B=4, S=1024, H=1024, NH=16, HD=64. fp32 in/out, bf16 MFMA inside.
// d_out = [out 4096x1024 f32] ++ [probs 64x1024x1024 f32]
// d_ws (64MB): qhi 8M | qlo 8M | khi 8M | klo 8M | vt 8M | ctxb 8M | hsb 8M | Wcat(q,k,v)+Wo 8M

typedef __attribute__((ext_vector_type(8))) short short8;
typedef __attribute__((ext_vector_type(4))) float f32x4;
typedef __attribute__((ext_vector_type(4))) short short4v;

#define LOG2E 1.44269504f
#define MFMA_BF16(a, b, c) __builtin_amdgcn_mfma_f32_16x16x32_bf16((a), (b), (c), 0, 0, 0)

__device__ __forceinline__ short f2bf(float x) {
    __hip_bfloat16 h = __float2bfloat16(x);
    return __builtin_bit_cast(short, h);
}
__device__ __forceinline__ float bf2f(short s) {
    __hip_bfloat16 h = __builtin_bit_cast(__hip_bfloat16, s);
    return __bfloat162float(h);
}

__device__ __forceinline__ void gload16(const void* g, void* lds) {
    __builtin_amdgcn_global_load_lds(
        (const __attribute__((address_space(1))) void*)g,
        (__attribute__((address_space(3))) void*)lds, 16, 0, 0);
}

// ---------------- fp32 -> bf16 converts ----------------
__global__ __launch_bounds__(256) void cvt_bf16_kernel(const float* __restrict__ src,
                                                       short* __restrict__ dst, int n8) {
    int i = blockIdx.x * 256 + threadIdx.x;
    if (i >= n8) return;
    const float4* s = (const float4*)src;
    float4 a = s[i * 2], b = s[i * 2 + 1];
    short8 o;
    o[0] = f2bf(a.x); o[1] = f2bf(a.y); o[2] = f2bf(a.z); o[3] = f2bf(a.w);
    o[4] = f2bf(b.x); o[5] = f2bf(b.y); o[6] = f2bf(b.z); o[7] = f2bf(b.w);
    *(short8*)(dst + (size_t)i * 8) = o;
}

// 4 weight matrices (1M f32 each) -> contiguous bf16 [4*1024][1024]
__global__ __launch_bounds__(256) void cvt4_kernel(const float* __restrict__ s0,
                                                   const float* __restrict__ s1,
                                                   const float* __restrict__ s2,
                                                   const float* __restrict__ s3,
                                                   short* __restrict__ dst) {
    int sel = blockIdx.x >> 9;                    // 512 blocks per weight
    const float* srcs[4] = {s0, s1, s2, s3};
    const float* s = srcs[sel];
    int li = (blockIdx.x & 511) * 256 + threadIdx.x;   // 8-group index within weight
    const float4* sp = (const float4*)s;
    float4 a = sp[li * 2], b = sp[li * 2 + 1];
    short8 o;
    o[0] = f2bf(a.x); o[1] = f2bf(a.y); o[2] = f2bf(a.z); o[3] = f2bf(a.w);
    o[4] = f2bf(b.x); o[5] = f2bf(b.y); o[6] = f2bf(b.z); o[7] = f2bf(b.w);
    *(short8*)(dst + ((size_t)sel * 131072 + li) * 8) = o;
}

// ---------------- 128x128-tile double-buffered NT GEMM, K=1024 ----------------
// EPI 0: Cf = A@B^T + bias (f32 row-major, B=Wo, N=1024)
// EPI 1: QKV combined: n0<1024 -> Q hi/lo (*0.125); <2048 -> K hi/lo; else V->vt
template <int EPI>
__global__ __launch_bounds__(256) void gemm128_kernel(
    const short* __restrict__ A, const short* __restrict__ B,
    float* __restrict__ Cf, const float* __restrict__ bias0,
    short* __restrict__ qhi, short* __restrict__ qlo,
    short* __restrict__ khi, short* __restrict__ klo, short* __restrict__ vt,
    const float* __restrict__ biasq, const float* __restrict__ biask,
    const float* __restrict__ biasv)
{
    __shared__ short As[2][128][32];   // 16 KB
    __shared__ short Bs[2][128][32];   // 16 KB
    int tid = threadIdx.x;
    int l = tid & 63, w = tid >> 6;
    int lr = l & 15, lg = l >> 4;
    int wm = w >> 1, wn = w & 1;
    int m0 = blockIdx.y * 128, n0 = blockIdx.x * 128;

    f32x4 acc[4][4] = {};

    int sr = l >> 2;                 // staging row within 16-row chunk
    int sc = (l & 3) * 16;           // byte col within 64B row
    const char* Ag = (const char*)A + ((size_t)(m0 + w * 32 + sr) * 1024) * 2 + sc;
    const char* Bg = (const char*)B + ((size_t)(n0 + w * 32 + sr) * 1024) * 2 + sc;

    auto stage = [&](int buf, int t) {
        int kb = t * 64;             // byte offset of k0 (=t*32 elements * 2B)
        #pragma unroll
        for (int g = 0; g < 2; ++g) {
            gload16(Ag + (size_t)g * (16 * 2048) + kb, (char*)&As[buf][w * 32 + g * 16][0]);
            gload16(Bg + (size_t)g * (16 * 2048) + kb, (char*)&Bs[buf][w * 32 + g * 16][0]);
        }
    };

    stage(0, 0);
    __syncthreads();

    int cur = 0;
    for (int t = 0; t < 32; ++t) {
        if (t < 31) stage(cur ^ 1, t + 1);
        short8 a[4], b[4];
        #pragma unroll
        for (int i = 0; i < 4; ++i)
            a[i] = *(const short8*)&As[cur][wm * 64 + i * 16 + lr][lg * 8];
        #pragma unroll
        for (int j = 0; j < 4; ++j)
            b[j] = *(const short8*)&Bs[cur][wn * 64 + j * 16 + lr][lg * 8];
        #pragma unroll
        for (int i = 0; i < 4; ++i)
            #pragma unroll
            for (int j = 0; j < 4; ++j)
                acc[i][j] = MFMA_BF16(a[i], b[j], acc[i][j]);
        __syncthreads();
        cur ^= 1;
    }

    if (EPI == 0) {
        #pragma unroll
        for (int i = 0; i < 4; ++i) {
            int m_base = m0 + wm * 64 + i * 16 + lg * 4;
            #pragma unroll
            for (int j = 0; j < 4; ++j) {
                int n = n0 + wn * 64 + j * 16 + lr;
                float bv = bias0[n];
                #pragma unroll
                for (int r = 0; r < 4; ++r)
                    Cf[(size_t)(m_base + r) * 1024 + n] = acc[i][j][r] + bv;
            }
        }
    } else {
        int sel = n0 >> 10;          // 0=Q, 1=K, 2=V (uniform per block)
        if (sel == 2) {
            #pragma unroll
            for (int i = 0; i < 4; ++i) {
                int m_base = m0 + wm * 64 + i * 16 + lg * 4;
                int b_ = m_base >> 10, s = m_base & 1023;
                #pragma unroll
                for (int j = 0; j < 4; ++j) {
                    int n = (n0 & 1023) + wn * 64 + j * 16 + lr;
                    float bv = biasv[n];
                    int h = n >> 6, d = n & 63;
                    short4v o;
                    #pragma unroll
                    for (int r = 0; r < 4; ++r) o[r] = f2bf(acc[i][j][r] + bv);
                    *(short4v*)(vt + ((size_t)((b_ * 16 + h) * 64 + d) * 1024 + s)) = o;
                }
            }
        } else {
            short* Chi = sel ? khi : qhi;
            short* Clo = sel ? klo : qlo;
            const float* bias = sel ? biask : biasq;
            float ps = sel ? 1.0f : 0.125f;
            #pragma unroll
            for (int i = 0; i < 4; ++i) {
                int m_base = m0 + wm * 64 + i * 16 + lg * 4;
                #pragma unroll
                for (int j = 0; j < 4; ++j) {
                    int n = (n0 & 1023) + wn * 64 + j * 16 + lr;
                    float bv = bias[n];
                    #pragma unroll
                    for (int r = 0; r < 4; ++r) {
                        float v = (acc[i][j][r] + bv) * ps;
                        short hh = f2bf(v);
                        short ll = f2bf(v - bf2f(hh));
                        Chi[(size_t)(m_base + r) * 1024 + n] = hh;
                        Clo[(size_t)(m_base + r) * 1024 + n] = ll;
                    }
                }
            }
        }
    }
}

// -------- fused scores+softmax: probs[z][q][k] = softmax((Q K^T)/8 + maskadd) --------
__global__ __launch_bounds__(256) void attn_fused_kernel(
    const short* __restrict__ Qhi, const short* __restrict__ Qlo,
    const short* __restrict__ Khi, const short* __restrict__ Klo,
    const float* __restrict__ mask, float* __restrict__ P)
{
    constexpr int QHI_O = 0, QLO_O = 4096, KHI_O = 8192, KLO_O = 24576,
                  MADD_O = 40960, WRM_O = 45056, WRL_O = 45568;
    __shared__ __align__(16) char lds[46080];

    int tid = threadIdx.x;
    int l = tid & 63, w = tid >> 6;
    int c = l & 15, g = l >> 4;
    int z = blockIdx.y;
    int b = z >> 4, h = z & 15;
    int qb = blockIdx.x;

    {
        const float4* mrow = (const float4*)(mask + b * 1024);
        float4 mm = mrow[tid];
        float4 md;
        md.x = (1.0f - mm.x) * -10000.0f;
        md.y = (1.0f - mm.y) * -10000.0f;
        md.z = (1.0f - mm.z) * -10000.0f;
        md.w = (1.0f - mm.w) * -10000.0f;
        *(float4*)(lds + MADD_O + tid * 16) = md;
    }

    {
        int r_ = w * 8 + (l >> 3);
        int ul = (l & 7) ^ (r_ & 7);
        size_t gq = ((size_t)(b * 1024 + qb * 32 + r_)) * 1024 + h * 64 + ul * 8;
        gload16(Qhi + gq, lds + QHI_O + w * 1024);
        gload16(Qlo + gq, lds + QLO_O + w * 1024);
    }
    asm volatile("s_waitcnt vmcnt(0)" ::: "memory");
    __syncthreads();

    short8 bqh[2][2], bql[2][2];
    #pragma unroll
    for (int qt = 0; qt < 2; ++qt) {
        int row = qt * 16 + c;
        #pragma unroll
        for (int dt = 0; dt < 2; ++dt) {
            int u = (dt * 4 + g) ^ (row & 7);
            bqh[qt][dt] = *(const short8*)(lds + QHI_O + row * 128 + u * 16);
            bql[qt][dt] = *(const short8*)(lds + QLO_O + row * 128 + u * 16);
        }
    }

    f32x4 acc[8][2][2] = {};

    #pragma unroll
    for (int cc = 0; cc < 8; ++cc) {
        #pragma unroll
        for (int i = 0; i < 4; ++i) {
            int r_ = i * 32 + w * 8 + (l >> 3);
            int ul = (l & 7) ^ (r_ & 7);
            size_t gk = ((size_t)(b * 1024 + cc * 128 + r_)) * 1024 + h * 64 + ul * 8;
            gload16(Khi + gk, lds + KHI_O + i * 4096 + w * 1024);
            gload16(Klo + gk, lds + KLO_O + i * 4096 + w * 1024);
        }
        asm volatile("s_waitcnt vmcnt(0)" ::: "memory");
        __syncthreads();

        #pragma unroll
        for (int kt = 0; kt < 2; ++kt) {
            int row = w * 32 + kt * 16 + c;
            #pragma unroll
            for (int dt = 0; dt < 2; ++dt) {
                int u = (dt * 4 + g) ^ (row & 7);
                short8 ah = *(const short8*)(lds + KHI_O + row * 128 + u * 16);
                short8 al = *(const short8*)(lds + KLO_O + row * 128 + u * 16);
                #pragma unroll
                for (int qt = 0; qt < 2; ++qt) {
                    acc[cc][kt][qt] = MFMA_BF16(ah, bqh[qt][dt], acc[cc][kt][qt]);
                    acc[cc][kt][qt] = MFMA_BF16(ah, bql[qt][dt], acc[cc][kt][qt]);
                    acc[cc][kt][qt] = MFMA_BF16(al, bqh[qt][dt], acc[cc][kt][qt]);
                }
            }
        }
        __syncthreads();
    }

    float mx[2] = {-3.0e38f, -3.0e38f};
    #pragma unroll
    for (int cc = 0; cc < 8; ++cc)
        #pragma unroll
        for (int kt = 0; kt < 2; ++kt) {
            f32x4 md = *(const f32x4*)(lds + MADD_O + (cc * 128 + w * 32 + kt * 16 + g * 4) * 4);
            #pragma unroll
            for (int qt = 0; qt < 2; ++qt) {
                f32x4 v = acc[cc][kt][qt] + md;
                acc[cc][kt][qt] = v;
                mx[qt] = fmaxf(mx[qt], fmaxf(fmaxf(v[0], v[1]), fmaxf(v[2], v[3])));
            }
        }
    #pragma unroll
    for (int qt = 0; qt < 2; ++qt) {
        mx[qt] = fmaxf(mx[qt], __shfl_xor(mx[qt], 16));
        mx[qt] = fmaxf(mx[qt], __shfl_xor(mx[qt], 32));
    }
    float* wrm = (float*)(lds + WRM_O);
    float* wrl = (float*)(lds + WRL_O);
    if (g == 0) { wrm[w * 32 + c] = mx[0]; wrm[w * 32 + 16 + c] = mx[1]; }
    __syncthreads();
    float mfin[2];
    mfin[0] = fmaxf(fmaxf(wrm[c], wrm[32 + c]), fmaxf(wrm[64 + c], wrm[96 + c]));
    mfin[1] = fmaxf(fmaxf(wrm[16 + c], wrm[48 + c]), fmaxf(wrm[80 + c], wrm[112 + c]));

    float sum[2] = {0.0f, 0.0f};
    #pragma unroll
    for (int cc = 0; cc < 8; ++cc)
        #pragma unroll
        for (int kt = 0; kt < 2; ++kt)
            #pragma unroll
            for (int qt = 0; qt < 2; ++qt) {
                f32x4 v = acc[cc][kt][qt];
                v[0] = exp2f((v[0] - mfin[qt]) * LOG2E);
                v[1] = exp2f((v[1] - mfin[qt]) * LOG2E);
                v[2] = exp2f((v[2] - mfin[qt]) * LOG2E);
                v[3] = exp2f((v[3] - mfin[qt]) * LOG2E);
                acc[cc][kt][qt] = v;
                sum[qt] += (v[0] + v[1]) + (v[2] + v[3]);
            }
    #pragma unroll
    for (int qt = 0; qt < 2; ++qt) {
        sum[qt] += __shfl_xor(sum[qt], 16);
        sum[qt] += __shfl_xor(sum[qt], 32);
    }
    if (g == 0) { wrl[w * 32 + c] = sum[0]; wrl[w * 32 + 16 + c] = sum[1]; }
    __syncthreads();
    float inv[2];
    inv[0] = 1.0f / ((wrl[c] + wrl[32 + c]) + (wrl[64 + c] + wrl[96 + c]));
    inv[1] = 1.0f / ((wrl[16 + c] + wrl[48 + c]) + (wrl[80 + c] + wrl[112 + c]));

    float* Pz = P + ((size_t)z << 20);
    #pragma unroll
    for (int cc = 0; cc < 8; ++cc)
        #pragma unroll
        for (int kt = 0; kt < 2; ++kt)
            #pragma unroll
            for (int qt = 0; qt < 2; ++qt) {
                f32x4 v = acc[cc][kt][qt];
                v[0] *= inv[qt]; v[1] *= inv[qt]; v[2] *= inv[qt]; v[3] *= inv[qt];
                int q = qb * 32 + qt * 16 + c;
                int k = cc * 128 + w * 32 + kt * 16 + g * 4;
                *(f32x4*)(Pz + (size_t)q * 1024 + k) = v;
            }
}

// ---------------- ctx = probs @ V, double-buffered ----------------
__global__ __launch_bounds__(256) void pv_kernel(
    const float* __restrict__ P, const short* __restrict__ Vt,
    short* __restrict__ Ctx)
{
    __shared__ float Ps[2][128][32];   // 32 KB
    __shared__ short Vs[2][64][32];    // 8 KB
    int tid = threadIdx.x, l = tid & 63, w = tid >> 6;
    int lr = l & 15, lg = l >> 4;
    int z = blockIdx.y;
    int b_ = z >> 4, h = z & 15;
    int m0 = blockIdx.x * 128;

    const char* Pg = (const char*)(P + (size_t)z * 1048576)
                   + (size_t)(m0 + w * 32 + (l >> 3)) * 4096 + (l & 7) * 16;
    const char* Vg = (const char*)(Vt + (size_t)z * 65536)
                   + (size_t)(w * 16 + (l >> 2)) * 2048 + (l & 3) * 16;

    auto stage = [&](int buf, int t) {
        #pragma unroll
        for (int g = 0; g < 4; ++g)
            gload16(Pg + (size_t)g * (8 * 4096) + t * 128, (char*)&Ps[buf][w * 32 + g * 8][0]);
        gload16(Vg + t * 64, (char*)&Vs[buf][w * 16][0]);
    };

    f32x4 acc[2][4] = {};
    stage(0, 0);
    __syncthreads();

    int cur = 0;
    for (int t = 0; t < 32; ++t) {
        if (t < 31) stage(cur ^ 1, t + 1);
        short8 a[2], b[4];
        #pragma unroll
        for (int i = 0; i < 2; ++i) {
            const float* p = &Ps[cur][w * 32 + i * 16 + lr][lg * 8];
            f32x4 x0 = *(const f32x4*)p, x1 = *(const f32x4*)(p + 4);
            a[i][0] = f2bf(x0[0]); a[i][1] = f2bf(x0[1]);
            a[i][2] = f2bf(x0[2]); a[i][3] = f2bf(x0[3]);
            a[i][4] = f2bf(x1[0]); a[i][5] = f2bf(x1[1]);
            a[i][6] = f2bf(x1[2]); a[i][7] = f2bf(x1[3]);
        }
        #pragma unroll
        for (int j = 0; j < 4; ++j)
            b[j] = *(const short8*)&Vs[cur][j * 16 + lr][lg * 8];
        #pragma unroll
        for (int i = 0; i < 2; ++i)
            #pragma unroll
            for (int j = 0; j < 4; ++j)
                acc[i][j] = MFMA_BF16(a[i], b[j], acc[i][j]);
        __syncthreads();
        cur ^= 1;
    }

    #pragma unroll
    for (int i = 0; i < 2; ++i) {
        int m_base = m0 + w * 32 + i * 16 + lg * 4;
        #pragma unroll
        for (int j = 0; j < 4; ++j) {
            int n = j * 16 + lr;
            size_t base = ((size_t)(b_ * 1024) + m_base) * 1024 + h * 64 + n;
            #pragma unroll
            for (int r = 0; r < 4; ++r)
                Ctx[base + (size_t)r * 1024] = f2bf(acc[i][j][r]);
        }
    }
}

extern "C" void kernel_launch(void* const* d_in, const int* in_sizes, int n_in,
                              void* d_out, int out_size, void* d_ws, size_t ws_size,
                              hipStream_t stream) {
    const float* hs   = (const float*)d_in[0];
    const float* mask = (const float*)d_in[1];
    const float* Wq   = (const float*)d_in[2];
    const float* bq   = (const float*)d_in[3];
    const float* Wk   = (const float*)d_in[4];
    const float* bk   = (const float*)d_in[5];
    const float* Wv   = (const float*)d_in[6];
    const float* bv   = (const float*)d_in[7];
    const float* Wo   = (const float*)d_in[8];
    const float* bo   = (const float*)d_in[9];

    float* out   = (float*)d_out;
    float* probs = out + 4194304;

    char* ws = (char*)d_ws;
    short* qhi  = (short*)(ws);
    short* qlo  = (short*)(ws + (8u << 20));
    short* khi  = (short*)(ws + (16u << 20));
    short* klo  = (short*)(ws + (24u << 20));
    short* vt   = (short*)(ws + (32u << 20));
    short* ctxb = (short*)(ws + (40u << 20));
    short* hsb  = (short*)(ws + (48u << 20));
    short* wcat = (short*)(ws + (56u << 20));   // Wq|Wk|Wv|Wo bf16, [4096][1024]
    short* wob  = wcat + 3 * (1u << 20);

    dim3 blk(256);

    cvt_bf16_kernel<<<2048, blk, 0, stream>>>(hs, hsb, 524288);
    cvt4_kernel<<<2048, blk, 0, stream>>>(Wq, Wk, Wv, Wo, wcat);

    // fused QKV projection: [4096][1024] @ [3072][1024]^T
    gemm128_kernel<1><<<dim3(24, 32), blk, 0, stream>>>(
        hsb, wcat, nullptr, nullptr, qhi, qlo, khi, klo, vt, bq, bk, bv);

    // fused scores+softmax -> probs
    attn_fused_kernel<<<dim3(32, 64), blk, 0, stream>>>(qhi, qlo, khi, klo, mask, probs);

    // ctx = probs @ V
    pv_kernel<<<dim3(8, 64), blk, 0, stream>>>(probs, vt, ctxb);

    // out = ctx @ Wo^T + bo
    gemm128_kernel<0><<<dim3(8, 32), blk, 0, stream>>>(
        ctxb, wob, out, bo, nullptr, nullptr, nullptr, nullptr, nullptr,
        nullptr, nullptr, nullptr);
}

// Round 6
// 212.400 us; speedup vs baseline: 5.4491x; 1.2877x over previous
//
#include <hip/hip_runtime.h>
#include <hip/hip_bf16.h>

// MHA fwd: B=4, S=1024, H=1024, NH=16, HD=64. fp32 in/out, bf16 MFMA inside.
// d_out = [out 4096x1024 f32] ++ [probs 64x1024x1024 f32]
// d_ws (64MB): qhi 8M | qlo 8M | khi 8M | klo 8M | vt 8M | ctxb 8M | hsb 8M | Wcat 8M

typedef __attribute__((ext_vector_type(8))) short short8;
typedef __attribute__((ext_vector_type(4))) float f32x4;
typedef __attribute__((ext_vector_type(4))) short short4v;

#define LOG2E 1.44269504f
#define MFMA_BF16(a, b, c) __builtin_amdgcn_mfma_f32_16x16x32_bf16((a), (b), (c), 0, 0, 0)

__device__ __forceinline__ short f2bf(float x) {
    __hip_bfloat16 h = __float2bfloat16(x);
    return __builtin_bit_cast(short, h);
}
__device__ __forceinline__ float bf2f(short s) {
    __hip_bfloat16 h = __builtin_bit_cast(__hip_bfloat16, s);
    return __bfloat162float(h);
}

__device__ __forceinline__ void gload16(const void* g, void* lds) {
    __builtin_amdgcn_global_load_lds(
        (const __attribute__((address_space(1))) void*)g,
        (__attribute__((address_space(3))) void*)lds, 16, 0, 0);
}

// ---------------- fp32 -> bf16 converts ----------------
__global__ __launch_bounds__(256) void cvt_bf16_kernel(const float* __restrict__ src,
                                                       short* __restrict__ dst, int n8) {
    int i = blockIdx.x * 256 + threadIdx.x;
    if (i >= n8) return;
    const float4* s = (const float4*)src;
    float4 a = s[i * 2], b = s[i * 2 + 1];
    short8 o;
    o[0] = f2bf(a.x); o[1] = f2bf(a.y); o[2] = f2bf(a.z); o[3] = f2bf(a.w);
    o[4] = f2bf(b.x); o[5] = f2bf(b.y); o[6] = f2bf(b.z); o[7] = f2bf(b.w);
    *(short8*)(dst + (size_t)i * 8) = o;
}

__global__ __launch_bounds__(256) void cvt4_kernel(const float* __restrict__ s0,
                                                   const float* __restrict__ s1,
                                                   const float* __restrict__ s2,
                                                   const float* __restrict__ s3,
                                                   short* __restrict__ dst) {
    int sel = blockIdx.x >> 9;
    const float* srcs[4] = {s0, s1, s2, s3};
    const float* s = srcs[sel];
    int li = (blockIdx.x & 511) * 256 + threadIdx.x;
    const float4* sp = (const float4*)s;
    float4 a = sp[li * 2], b = sp[li * 2 + 1];
    short8 o;
    o[0] = f2bf(a.x); o[1] = f2bf(a.y); o[2] = f2bf(a.z); o[3] = f2bf(a.w);
    o[4] = f2bf(b.x); o[5] = f2bf(b.y); o[6] = f2bf(b.z); o[7] = f2bf(b.w);
    *(short8*)(dst + ((size_t)sel * 131072 + li) * 8) = o;
}

// ---------------- 128x128-tile double-buffered NT GEMM, K=1024 ----------------
// EPI 0: Cf = A@B^T + bias (f32 row-major)
// EPI 1: QKV: n0<1024 -> Q hi/lo (*0.125); <2048 -> K hi/lo; else V->vt. LDS-bounce stores.
template <int EPI>
__global__ __launch_bounds__(256) void gemm128_kernel(
    const short* __restrict__ A, const short* __restrict__ B,
    float* __restrict__ Cf, const float* __restrict__ bias0,
    short* __restrict__ qhi, short* __restrict__ qlo,
    short* __restrict__ khi, short* __restrict__ klo, short* __restrict__ vt,
    const float* __restrict__ biasq, const float* __restrict__ biask,
    const float* __restrict__ biasv)
{
    __shared__ short smem[16384];   // 32KB: As/Bs staging; reused as epilogue bounce
    int tid = threadIdx.x;
    int l = tid & 63, w = tid >> 6;
    int lr = l & 15, lg = l >> 4;
    int wm = w >> 1, wn = w & 1;
    int m0 = blockIdx.y * 128, n0 = blockIdx.x * 128;

    f32x4 acc[4][4] = {};

    int sr = l >> 2;
    int sc = (l & 3) * 16;
    const char* Ag = (const char*)A + ((size_t)(m0 + w * 32 + sr) * 1024) * 2 + sc;
    const char* Bg = (const char*)B + ((size_t)(n0 + w * 32 + sr) * 1024) * 2 + sc;

    auto stage = [&](int buf, int t) {
        int kb = t * 64;
        #pragma unroll
        for (int g = 0; g < 2; ++g) {
            gload16(Ag + (size_t)g * (16 * 2048) + kb,
                    (char*)&smem[buf * 4096 + (w * 32 + g * 16) * 32]);
            gload16(Bg + (size_t)g * (16 * 2048) + kb,
                    (char*)&smem[8192 + buf * 4096 + (w * 32 + g * 16) * 32]);
        }
    };

    stage(0, 0);
    __syncthreads();

    int cur = 0;
    for (int t = 0; t < 32; ++t) {
        if (t < 31) stage(cur ^ 1, t + 1);
        short8 a[4], b[4];
        #pragma unroll
        for (int i = 0; i < 4; ++i)
            a[i] = *(const short8*)&smem[cur * 4096 + (wm * 64 + i * 16 + lr) * 32 + lg * 8];
        #pragma unroll
        for (int j = 0; j < 4; ++j)
            b[j] = *(const short8*)&smem[8192 + cur * 4096 + (wn * 64 + j * 16 + lr) * 32 + lg * 8];
        #pragma unroll
        for (int i = 0; i < 4; ++i)
            #pragma unroll
            for (int j = 0; j < 4; ++j)
                acc[i][j] = MFMA_BF16(a[i], b[j], acc[i][j]);
        __syncthreads();
        cur ^= 1;
    }

    if (EPI == 0) {
        #pragma unroll
        for (int i = 0; i < 4; ++i) {
            int m_base = m0 + wm * 64 + i * 16 + lg * 4;
            #pragma unroll
            for (int j = 0; j < 4; ++j) {
                int n = n0 + wn * 64 + j * 16 + lr;
                float bv = bias0[n];
                #pragma unroll
                for (int r = 0; r < 4; ++r)
                    Cf[(size_t)(m_base + r) * 1024 + n] = acc[i][j][r] + bv;
            }
        }
    } else {
        int sel = n0 >> 10;
        int nb = n0 & 1023;
        if (sel == 2) {
            // V: transpose to vt[(b*16+h)*64+d][s], bounced through LDS [n][m] swizzled
            #pragma unroll
            for (int i = 0; i < 4; ++i) {
                int ml = wm * 64 + i * 16 + lg * 4;
                #pragma unroll
                for (int j = 0; j < 4; ++j) {
                    int nl = wn * 64 + j * 16 + lr;
                    float bvv = biasv[nb + nl];
                    short4v o;
                    #pragma unroll
                    for (int r = 0; r < 4; ++r) o[r] = f2bf(acc[i][j][r] + bvv);
                    *(short4v*)((char*)smem + nl * 256 + ((ml * 2) ^ ((nl & 7) << 4))) = o;
                }
            }
            __syncthreads();
            int b_ = m0 >> 10, s0 = m0 & 1023;
            #pragma unroll
            for (int it = 0; it < 8; ++it) {
                int idx = it * 256 + tid;
                int nrow = idx >> 4, c8 = idx & 15;
                short8 vv = *(const short8*)((char*)smem + nrow * 256 +
                                             ((c8 * 16) ^ ((nrow & 7) << 4)));
                int ng = nb + nrow;
                int h = ng >> 6, d = ng & 63;
                *(short8*)(vt + (size_t)((b_ * 16 + h) * 64 + d) * 1024 + s0 + c8 * 8) = vv;
            }
        } else {
            short* Chi = sel ? khi : qhi;
            short* Clo = sel ? klo : qlo;
            const float* bias = sel ? biask : biasq;
            float ps = sel ? 1.0f : 0.125f;
            #pragma unroll
            for (int hv = 0; hv < 2; ++hv) {
                __syncthreads();
                #pragma unroll
                for (int i = 0; i < 4; ++i) {
                    int ml = wm * 64 + i * 16 + lg * 4;
                    #pragma unroll
                    for (int j = 0; j < 4; ++j) {
                        int nl = wn * 64 + j * 16 + lr;
                        float bvv = bias[nb + nl];
                        #pragma unroll
                        for (int r = 0; r < 4; ++r) {
                            float v = (acc[i][j][r] + bvv) * ps;
                            short hh = f2bf(v);
                            short ss = hv ? f2bf(v - bf2f(hh)) : hh;
                            smem[(ml + r) * 128 + nl] = ss;
                        }
                    }
                }
                __syncthreads();
                short* dst = hv ? Clo : Chi;
                #pragma unroll
                for (int it = 0; it < 8; ++it) {
                    int idx = it * 256 + tid;
                    int row = idx >> 4, c8 = idx & 15;
                    short8 vv = *(const short8*)&smem[row * 128 + c8 * 8];
                    *(short8*)(dst + (size_t)(m0 + row) * 1024 + nb + c8 * 8) = vv;
                }
            }
        }
    }
}

// -------- fused scores+softmax+PV --------
// Block: 32 q-rows x full 1024 k, z = (b,h). Swapped mfma(K,Q): C[m=k][n=q].
// Writes probs f32 once; keeps bf16 P in LDS; then ctx = P@V with V streamed from L2.
__global__ __launch_bounds__(256) void attn_fused_kernel(
    const short* __restrict__ Qhi, const short* __restrict__ Qlo,
    const short* __restrict__ Khi, const short* __restrict__ Klo,
    const float* __restrict__ mask, float* __restrict__ P,
    const short* __restrict__ vt, short* __restrict__ ctxb)
{
    // [0,65536): P_lds (phase3+); overlays K staging [0,32768) + Q staging [32768,40960) (phase1)
    constexpr int P_O = 0, KHI_O = 0, KLO_O = 16384, QHI_O = 32768, QLO_O = 36864,
                  MADD_O = 65536, WRM_O = 69632, WRL_O = 70144;
    __shared__ __align__(16) char lds[70656];

    int tid = threadIdx.x;
    int l = tid & 63, w = tid >> 6;
    int c = l & 15, g = l >> 4;
    int z = blockIdx.y;
    int b = z >> 4, h = z & 15;
    int qb = blockIdx.x;

    {
        const float4* mrow = (const float4*)(mask + b * 1024);
        float4 mm = mrow[tid];
        float4 md;
        md.x = (1.0f - mm.x) * -10000.0f;
        md.y = (1.0f - mm.y) * -10000.0f;
        md.z = (1.0f - mm.z) * -10000.0f;
        md.w = (1.0f - mm.w) * -10000.0f;
        *(float4*)(lds + MADD_O + tid * 16) = md;
    }

    {
        int r_ = w * 8 + (l >> 3);
        int ul = (l & 7) ^ (r_ & 7);
        size_t gq = ((size_t)(b * 1024 + qb * 32 + r_)) * 1024 + h * 64 + ul * 8;
        gload16(Qhi + gq, lds + QHI_O + w * 1024);
        gload16(Qlo + gq, lds + QLO_O + w * 1024);
    }
    asm volatile("s_waitcnt vmcnt(0)" ::: "memory");
    __syncthreads();

    short8 bqh[2][2], bql[2][2];
    #pragma unroll
    for (int qt = 0; qt < 2; ++qt) {
        int row = qt * 16 + c;
        #pragma unroll
        for (int dt = 0; dt < 2; ++dt) {
            int u = (dt * 4 + g) ^ (row & 7);
            bqh[qt][dt] = *(const short8*)(lds + QHI_O + row * 128 + u * 16);
            bql[qt][dt] = *(const short8*)(lds + QLO_O + row * 128 + u * 16);
        }
    }

    f32x4 acc[8][2][2] = {};

    #pragma unroll
    for (int cc = 0; cc < 8; ++cc) {
        #pragma unroll
        for (int i = 0; i < 4; ++i) {
            int r_ = i * 32 + w * 8 + (l >> 3);
            int ul = (l & 7) ^ (r_ & 7);
            size_t gk = ((size_t)(b * 1024 + cc * 128 + r_)) * 1024 + h * 64 + ul * 8;
            gload16(Khi + gk, lds + KHI_O + i * 4096 + w * 1024);
            gload16(Klo + gk, lds + KLO_O + i * 4096 + w * 1024);
        }
        asm volatile("s_waitcnt vmcnt(0)" ::: "memory");
        __syncthreads();

        #pragma unroll
        for (int kt = 0; kt < 2; ++kt) {
            int row = w * 32 + kt * 16 + c;
            #pragma unroll
            for (int dt = 0; dt < 2; ++dt) {
                int u = (dt * 4 + g) ^ (row & 7);
                short8 ah = *(const short8*)(lds + KHI_O + row * 128 + u * 16);
                short8 al = *(const short8*)(lds + KLO_O + row * 128 + u * 16);
                #pragma unroll
                for (int qt = 0; qt < 2; ++qt) {
                    acc[cc][kt][qt] = MFMA_BF16(ah, bqh[qt][dt], acc[cc][kt][qt]);
                    acc[cc][kt][qt] = MFMA_BF16(ah, bql[qt][dt], acc[cc][kt][qt]);
                    acc[cc][kt][qt] = MFMA_BF16(al, bqh[qt][dt], acc[cc][kt][qt]);
                }
            }
        }
        __syncthreads();
    }

    // softmax
    float mx[2] = {-3.0e38f, -3.0e38f};
    #pragma unroll
    for (int cc = 0; cc < 8; ++cc)
        #pragma unroll
        for (int kt = 0; kt < 2; ++kt) {
            f32x4 md = *(const f32x4*)(lds + MADD_O + (cc * 128 + w * 32 + kt * 16 + g * 4) * 4);
            #pragma unroll
            for (int qt = 0; qt < 2; ++qt) {
                f32x4 v = acc[cc][kt][qt] + md;
                acc[cc][kt][qt] = v;
                mx[qt] = fmaxf(mx[qt], fmaxf(fmaxf(v[0], v[1]), fmaxf(v[2], v[3])));
            }
        }
    #pragma unroll
    for (int qt = 0; qt < 2; ++qt) {
        mx[qt] = fmaxf(mx[qt], __shfl_xor(mx[qt], 16));
        mx[qt] = fmaxf(mx[qt], __shfl_xor(mx[qt], 32));
    }
    float* wrm = (float*)(lds + WRM_O);
    float* wrl = (float*)(lds + WRL_O);
    if (g == 0) { wrm[w * 32 + c] = mx[0]; wrm[w * 32 + 16 + c] = mx[1]; }
    __syncthreads();
    float mfin[2];
    mfin[0] = fmaxf(fmaxf(wrm[c], wrm[32 + c]), fmaxf(wrm[64 + c], wrm[96 + c]));
    mfin[1] = fmaxf(fmaxf(wrm[16 + c], wrm[48 + c]), fmaxf(wrm[80 + c], wrm[112 + c]));

    float sum[2] = {0.0f, 0.0f};
    #pragma unroll
    for (int cc = 0; cc < 8; ++cc)
        #pragma unroll
        for (int kt = 0; kt < 2; ++kt)
            #pragma unroll
            for (int qt = 0; qt < 2; ++qt) {
                f32x4 v = acc[cc][kt][qt];
                v[0] = exp2f((v[0] - mfin[qt]) * LOG2E);
                v[1] = exp2f((v[1] - mfin[qt]) * LOG2E);
                v[2] = exp2f((v[2] - mfin[qt]) * LOG2E);
                v[3] = exp2f((v[3] - mfin[qt]) * LOG2E);
                acc[cc][kt][qt] = v;
                sum[qt] += (v[0] + v[1]) + (v[2] + v[3]);
            }
    #pragma unroll
    for (int qt = 0; qt < 2; ++qt) {
        sum[qt] += __shfl_xor(sum[qt], 16);
        sum[qt] += __shfl_xor(sum[qt], 32);
    }
    if (g == 0) { wrl[w * 32 + c] = sum[0]; wrl[w * 32 + 16 + c] = sum[1]; }
    __syncthreads();
    float inv[2];
    inv[0] = 1.0f / ((wrl[c] + wrl[32 + c]) + (wrl[64 + c] + wrl[96 + c]));
    inv[1] = 1.0f / ((wrl[16 + c] + wrl[48 + c]) + (wrl[80 + c] + wrl[112 + c]));

    // write probs f32 to global (row = qb*32 + local q) + bf16 P into LDS (local q, swizzled)
    float* Pz = P + ((size_t)z << 20);
    #pragma unroll
    for (int cc = 0; cc < 8; ++cc)
        #pragma unroll
        for (int kt = 0; kt < 2; ++kt)
            #pragma unroll
            for (int qt = 0; qt < 2; ++qt) {
                f32x4 v = acc[cc][kt][qt];
                v[0] *= inv[qt]; v[1] *= inv[qt]; v[2] *= inv[qt]; v[3] *= inv[qt];
                int q = qt * 16 + c;                 // local q within 32-row block
                int k = cc * 128 + w * 32 + kt * 16 + g * 4;
                *(f32x4*)(Pz + (size_t)(qb * 32 + q) * 1024 + k) = v;   // FIX: +qb*32
                short4v ps4;
                ps4[0] = f2bf(v[0]); ps4[1] = f2bf(v[1]);
                ps4[2] = f2bf(v[2]); ps4[3] = f2bf(v[3]);
                *(short4v*)(lds + P_O + q * 2048 + ((k * 2) ^ ((q & 7) << 4))) = ps4;
            }
    __syncthreads();

    // PV: ctx[32q][64d] = P @ V; wave w owns d = w*16 + c; V streamed from global (L2-hot)
    {
        const short* vbase = vt + (size_t)z * 65536 + (size_t)(w * 16 + c) * 1024 + g * 8;
        f32x4 pacc[2] = {};
        short8 vfrag = *(const short8*)vbase;
        for (int kc = 0; kc < 32; ++kc) {
            short8 vnext = {};
            if (kc < 31) vnext = *(const short8*)(vbase + (kc + 1) * 32);
            short8 pa[2];
            #pragma unroll
            for (int qt = 0; qt < 2; ++qt) {
                int q = qt * 16 + c;
                int kbyte = kc * 64 + g * 16;
                pa[qt] = *(const short8*)(lds + P_O + q * 2048 + (kbyte ^ ((q & 7) << 4)));
            }
            pacc[0] = MFMA_BF16(pa[0], vfrag, pacc[0]);
            pacc[1] = MFMA_BF16(pa[1], vfrag, pacc[1]);
            vfrag = vnext;
        }
        #pragma unroll
        for (int qt = 0; qt < 2; ++qt) {
            int s = qb * 32 + qt * 16 + g * 4;
            size_t base = ((size_t)b * 1024 + s) * 1024 + h * 64 + w * 16 + c;
            #pragma unroll
            for (int r = 0; r < 4; ++r)
                ctxb[base + (size_t)r * 1024] = f2bf(pacc[qt][r]);
        }
    }
}

extern "C" void kernel_launch(void* const* d_in, const int* in_sizes, int n_in,
                              void* d_out, int out_size, void* d_ws, size_t ws_size,
                              hipStream_t stream) {
    const float* hs   = (const float*)d_in[0];
    const float* mask = (const float*)d_in[1];
    const float* Wq   = (const float*)d_in[2];
    const float* bq   = (const float*)d_in[3];
    const float* Wk   = (const float*)d_in[4];
    const float* bk   = (const float*)d_in[5];
    const float* Wv   = (const float*)d_in[6];
    const float* bv   = (const float*)d_in[7];
    const float* Wo   = (const float*)d_in[8];
    const float* bo   = (const float*)d_in[9];

    float* out   = (float*)d_out;
    float* probs = out + 4194304;

    char* ws = (char*)d_ws;
    short* qhi  = (short*)(ws);
    short* qlo  = (short*)(ws + (8u << 20));
    short* khi  = (short*)(ws + (16u << 20));
    short* klo  = (short*)(ws + (24u << 20));
    short* vt   = (short*)(ws + (32u << 20));
    short* ctxb = (short*)(ws + (40u << 20));
    short* hsb  = (short*)(ws + (48u << 20));
    short* wcat = (short*)(ws + (56u << 20));   // Wq|Wk|Wv|Wo bf16
    short* wob  = wcat + 3 * (1u << 20);

    dim3 blk(256);

    cvt_bf16_kernel<<<2048, blk, 0, stream>>>(hs, hsb, 524288);
    cvt4_kernel<<<2048, blk, 0, stream>>>(Wq, Wk, Wv, Wo, wcat);

    // fused QKV projection: [4096][1024] @ [3072][1024]^T
    gemm128_kernel<1><<<dim3(24, 32), blk, 0, stream>>>(
        hsb, wcat, nullptr, nullptr, qhi, qlo, khi, klo, vt, bq, bk, bv);

    // fused scores+softmax+PV -> probs + ctx
    attn_fused_kernel<<<dim3(32, 64), blk, 0, stream>>>(qhi, qlo, khi, klo, mask, probs,
                                                        vt, ctxb);

    // out = ctx @ Wo^T + bo
    gemm128_kernel<0><<<dim3(8, 32), blk, 0, stream>>>(
        ctxb, wob, out, bo, nullptr, nullptr, nullptr, nullptr, nullptr,
        nullptr, nullptr, nullptr);
}

// Round 7
// 209.770 us; speedup vs baseline: 5.5174x; 1.0125x over previous
//
#include <hip/hip_runtime.h>
#include <hip/hip_bf16.h>

// MHA fwd: B=4, S=1024, H=1024, NH=16, HD=64. fp32 in/out, bf16 MFMA inside.
// d_out = [out 4096x1024 f32] ++ [probs 64x1024x1024 f32]
// d_ws (64MB): qhi 8M | qlo 8M | khi 8M | klo 8M | vt 8M | ctxb 8M | hsb 8M | Wcat 8M

typedef __attribute__((ext_vector_type(8))) short short8;
typedef __attribute__((ext_vector_type(4))) float f32x4;
typedef __attribute__((ext_vector_type(4))) short short4v;

#define LOG2E 1.44269504f
#define MFMA_BF16(a, b, c) __builtin_amdgcn_mfma_f32_16x16x32_bf16((a), (b), (c), 0, 0, 0)

__device__ __forceinline__ short f2bf(float x) {
    __hip_bfloat16 h = __float2bfloat16(x);
    return __builtin_bit_cast(short, h);
}
__device__ __forceinline__ float bf2f(short s) {
    __hip_bfloat16 h = __builtin_bit_cast(__hip_bfloat16, s);
    return __bfloat162float(h);
}

__device__ __forceinline__ void gload16(const void* g, void* lds) {
    __builtin_amdgcn_global_load_lds(
        (const __attribute__((address_space(1))) void*)g,
        (__attribute__((address_space(3))) void*)lds, 16, 0, 0);
}

// ---------------- fp32 -> bf16 converts ----------------
__global__ __launch_bounds__(256) void cvt_bf16_kernel(const float* __restrict__ src,
                                                       short* __restrict__ dst, int n8) {
    int i = blockIdx.x * 256 + threadIdx.x;
    if (i >= n8) return;
    const float4* s = (const float4*)src;
    float4 a = s[i * 2], b = s[i * 2 + 1];
    short8 o;
    o[0] = f2bf(a.x); o[1] = f2bf(a.y); o[2] = f2bf(a.z); o[3] = f2bf(a.w);
    o[4] = f2bf(b.x); o[5] = f2bf(b.y); o[6] = f2bf(b.z); o[7] = f2bf(b.w);
    *(short8*)(dst + (size_t)i * 8) = o;
}

__global__ __launch_bounds__(256) void cvt4_kernel(const float* __restrict__ s0,
                                                   const float* __restrict__ s1,
                                                   const float* __restrict__ s2,
                                                   const float* __restrict__ s3,
                                                   short* __restrict__ dst) {
    int sel = blockIdx.x >> 9;
    const float* srcs[4] = {s0, s1, s2, s3};
    const float* s = srcs[sel];
    int li = (blockIdx.x & 511) * 256 + threadIdx.x;
    const float4* sp = (const float4*)s;
    float4 a = sp[li * 2], b = sp[li * 2 + 1];
    short8 o;
    o[0] = f2bf(a.x); o[1] = f2bf(a.y); o[2] = f2bf(a.z); o[3] = f2bf(a.w);
    o[4] = f2bf(b.x); o[5] = f2bf(b.y); o[6] = f2bf(b.z); o[7] = f2bf(b.w);
    *(short8*)(dst + ((size_t)sel * 131072 + li) * 8) = o;
}

// ---------------- 128x128-tile double-buffered NT GEMM, K=1024 ----------------
// EPI 0: Cf = A@B^T + bias (f32 row-major)
// EPI 1: QKV: n0<1024 -> Q hi/lo (*0.125); <2048 -> K hi/lo; else V->vt. LDS-bounce stores.
template <int EPI>
__global__ __launch_bounds__(256) void gemm128_kernel(
    const short* __restrict__ A, const short* __restrict__ B,
    float* __restrict__ Cf, const float* __restrict__ bias0,
    short* __restrict__ qhi, short* __restrict__ qlo,
    short* __restrict__ khi, short* __restrict__ klo, short* __restrict__ vt,
    const float* __restrict__ biasq, const float* __restrict__ biask,
    const float* __restrict__ biasv)
{
    __shared__ short smem[16384];   // 32KB: As/Bs staging; reused as epilogue bounce
    int tid = threadIdx.x;
    int l = tid & 63, w = tid >> 6;
    int lr = l & 15, lg = l >> 4;
    int wm = w >> 1, wn = w & 1;
    int m0 = blockIdx.y * 128, n0 = blockIdx.x * 128;

    f32x4 acc[4][4] = {};

    int sr = l >> 2;
    int sc = (l & 3) * 16;
    const char* Ag = (const char*)A + ((size_t)(m0 + w * 32 + sr) * 1024) * 2 + sc;
    const char* Bg = (const char*)B + ((size_t)(n0 + w * 32 + sr) * 1024) * 2 + sc;

    auto stage = [&](int buf, int t) {
        int kb = t * 64;
        #pragma unroll
        for (int g = 0; g < 2; ++g) {
            gload16(Ag + (size_t)g * (16 * 2048) + kb,
                    (char*)&smem[buf * 4096 + (w * 32 + g * 16) * 32]);
            gload16(Bg + (size_t)g * (16 * 2048) + kb,
                    (char*)&smem[8192 + buf * 4096 + (w * 32 + g * 16) * 32]);
        }
    };

    stage(0, 0);
    __syncthreads();

    int cur = 0;
    for (int t = 0; t < 32; ++t) {
        if (t < 31) stage(cur ^ 1, t + 1);
        short8 a[4], b[4];
        #pragma unroll
        for (int i = 0; i < 4; ++i)
            a[i] = *(const short8*)&smem[cur * 4096 + (wm * 64 + i * 16 + lr) * 32 + lg * 8];
        #pragma unroll
        for (int j = 0; j < 4; ++j)
            b[j] = *(const short8*)&smem[8192 + cur * 4096 + (wn * 64 + j * 16 + lr) * 32 + lg * 8];
        #pragma unroll
        for (int i = 0; i < 4; ++i)
            #pragma unroll
            for (int j = 0; j < 4; ++j)
                acc[i][j] = MFMA_BF16(a[i], b[j], acc[i][j]);
        __syncthreads();
        cur ^= 1;
    }

    if (EPI == 0) {
        #pragma unroll
        for (int i = 0; i < 4; ++i) {
            int m_base = m0 + wm * 64 + i * 16 + lg * 4;
            #pragma unroll
            for (int j = 0; j < 4; ++j) {
                int n = n0 + wn * 64 + j * 16 + lr;
                float bv = bias0[n];
                #pragma unroll
                for (int r = 0; r < 4; ++r)
                    Cf[(size_t)(m_base + r) * 1024 + n] = acc[i][j][r] + bv;
            }
        }
    } else {
        int sel = n0 >> 10;
        int nb = n0 & 1023;
        if (sel == 2) {
            // V: transpose to vt[(b*16+h)*64+d][s], bounced through LDS [n][m] swizzled
            #pragma unroll
            for (int i = 0; i < 4; ++i) {
                int ml = wm * 64 + i * 16 + lg * 4;
                #pragma unroll
                for (int j = 0; j < 4; ++j) {
                    int nl = wn * 64 + j * 16 + lr;
                    float bvv = biasv[nb + nl];
                    short4v o;
                    #pragma unroll
                    for (int r = 0; r < 4; ++r) o[r] = f2bf(acc[i][j][r] + bvv);
                    *(short4v*)((char*)smem + nl * 256 + ((ml * 2) ^ ((nl & 7) << 4))) = o;
                }
            }
            __syncthreads();
            int b_ = m0 >> 10, s0 = m0 & 1023;
            #pragma unroll
            for (int it = 0; it < 8; ++it) {
                int idx = it * 256 + tid;
                int nrow = idx >> 4, c8 = idx & 15;
                short8 vv = *(const short8*)((char*)smem + nrow * 256 +
                                             ((c8 * 16) ^ ((nrow & 7) << 4)));
                int ng = nb + nrow;
                int h = ng >> 6, d = ng & 63;
                *(short8*)(vt + (size_t)((b_ * 16 + h) * 64 + d) * 1024 + s0 + c8 * 8) = vv;
            }
        } else {
            short* Chi = sel ? khi : qhi;
            short* Clo = sel ? klo : qlo;
            const float* bias = sel ? biask : biasq;
            float ps = sel ? 1.0f : 0.125f;
            #pragma unroll
            for (int hv = 0; hv < 2; ++hv) {
                __syncthreads();
                #pragma unroll
                for (int i = 0; i < 4; ++i) {
                    int ml = wm * 64 + i * 16 + lg * 4;
                    #pragma unroll
                    for (int j = 0; j < 4; ++j) {
                        int nl = wn * 64 + j * 16 + lr;
                        float bvv = bias[nb + nl];
                        #pragma unroll
                        for (int r = 0; r < 4; ++r) {
                            float v = (acc[i][j][r] + bvv) * ps;
                            short hh = f2bf(v);
                            short ss = hv ? f2bf(v - bf2f(hh)) : hh;
                            smem[(ml + r) * 128 + nl] = ss;
                        }
                    }
                }
                __syncthreads();
                short* dst = hv ? Clo : Chi;
                #pragma unroll
                for (int it = 0; it < 8; ++it) {
                    int idx = it * 256 + tid;
                    int row = idx >> 4, c8 = idx & 15;
                    short8 vv = *(const short8*)&smem[row * 128 + c8 * 8];
                    *(short8*)(dst + (size_t)(m0 + row) * 1024 + nb + c8 * 8) = vv;
                }
            }
        }
    }
}

// -------- fused scores+softmax+PV --------
// Block: 32 q-rows x full 1024 k, z = (b,h). Swapped mfma(K,Q): C[m=k][n=q].
// Writes probs f32 once; keeps bf16 P in LDS; then ctx = P@V with V streamed from L2.
__global__ __launch_bounds__(256) void attn_fused_kernel(
    const short* __restrict__ Qhi, const short* __restrict__ Qlo,
    const short* __restrict__ Khi, const short* __restrict__ Klo,
    const float* __restrict__ mask, float* __restrict__ P,
    const short* __restrict__ vt, short* __restrict__ ctxb)
{
    // [0,65536): P_lds (phase3+); overlays K staging [0,32768) + Q staging [32768,40960) (phase1)
    constexpr int P_O = 0, KHI_O = 0, KLO_O = 16384, QHI_O = 32768, QLO_O = 36864,
                  MADD_O = 65536, WRM_O = 69632, WRL_O = 70144;
    __shared__ __align__(16) char lds[70656];

    int tid = threadIdx.x;
    int l = tid & 63, w = tid >> 6;
    int c = l & 15, g = l >> 4;
    int z = blockIdx.y;
    int b = z >> 4, h = z & 15;
    int qb = blockIdx.x;

    {
        const float4* mrow = (const float4*)(mask + b * 1024);
        float4 mm = mrow[tid];
        float4 md;
        md.x = (1.0f - mm.x) * -10000.0f;
        md.y = (1.0f - mm.y) * -10000.0f;
        md.z = (1.0f - mm.z) * -10000.0f;
        md.w = (1.0f - mm.w) * -10000.0f;
        *(float4*)(lds + MADD_O + tid * 16) = md;
    }

    {
        int r_ = w * 8 + (l >> 3);
        int ul = (l & 7) ^ (r_ & 7);
        size_t gq = ((size_t)(b * 1024 + qb * 32 + r_)) * 1024 + h * 64 + ul * 8;
        gload16(Qhi + gq, lds + QHI_O + w * 1024);
        gload16(Qlo + gq, lds + QLO_O + w * 1024);
    }
    asm volatile("s_waitcnt vmcnt(0)" ::: "memory");
    __syncthreads();

    short8 bqh[2][2], bql[2][2];
    #pragma unroll
    for (int qt = 0; qt < 2; ++qt) {
        int row = qt * 16 + c;
        #pragma unroll
        for (int dt = 0; dt < 2; ++dt) {
            int u = (dt * 4 + g) ^ (row & 7);
            bqh[qt][dt] = *(const short8*)(lds + QHI_O + row * 128 + u * 16);
            bql[qt][dt] = *(const short8*)(lds + QLO_O + row * 128 + u * 16);
        }
    }

    f32x4 acc[8][2][2] = {};

    #pragma unroll
    for (int cc = 0; cc < 8; ++cc) {
        #pragma unroll
        for (int i = 0; i < 4; ++i) {
            int r_ = i * 32 + w * 8 + (l >> 3);
            int ul = (l & 7) ^ (r_ & 7);
            size_t gk = ((size_t)(b * 1024 + cc * 128 + r_)) * 1024 + h * 64 + ul * 8;
            gload16(Khi + gk, lds + KHI_O + i * 4096 + w * 1024);
            gload16(Klo + gk, lds + KLO_O + i * 4096 + w * 1024);
        }
        asm volatile("s_waitcnt vmcnt(0)" ::: "memory");
        __syncthreads();

        #pragma unroll
        for (int kt = 0; kt < 2; ++kt) {
            int row = w * 32 + kt * 16 + c;
            #pragma unroll
            for (int dt = 0; dt < 2; ++dt) {
                int u = (dt * 4 + g) ^ (row & 7);
                short8 ah = *(const short8*)(lds + KHI_O + row * 128 + u * 16);
                short8 al = *(const short8*)(lds + KLO_O + row * 128 + u * 16);
                #pragma unroll
                for (int qt = 0; qt < 2; ++qt) {
                    acc[cc][kt][qt] = MFMA_BF16(ah, bqh[qt][dt], acc[cc][kt][qt]);
                    acc[cc][kt][qt] = MFMA_BF16(ah, bql[qt][dt], acc[cc][kt][qt]);
                    acc[cc][kt][qt] = MFMA_BF16(al, bqh[qt][dt], acc[cc][kt][qt]);
                }
            }
        }
        __syncthreads();
    }

    // softmax
    float mx[2] = {-3.0e38f, -3.0e38f};
    #pragma unroll
    for (int cc = 0; cc < 8; ++cc)
        #pragma unroll
        for (int kt = 0; kt < 2; ++kt) {
            f32x4 md = *(const f32x4*)(lds + MADD_O + (cc * 128 + w * 32 + kt * 16 + g * 4) * 4);
            #pragma unroll
            for (int qt = 0; qt < 2; ++qt) {
                f32x4 v = acc[cc][kt][qt] + md;
                acc[cc][kt][qt] = v;
                mx[qt] = fmaxf(mx[qt], fmaxf(fmaxf(v[0], v[1]), fmaxf(v[2], v[3])));
            }
        }
    #pragma unroll
    for (int qt = 0; qt < 2; ++qt) {
        mx[qt] = fmaxf(mx[qt], __shfl_xor(mx[qt], 16));
        mx[qt] = fmaxf(mx[qt], __shfl_xor(mx[qt], 32));
    }
    float* wrm = (float*)(lds + WRM_O);
    float* wrl = (float*)(lds + WRL_O);
    if (g == 0) { wrm[w * 32 + c] = mx[0]; wrm[w * 32 + 16 + c] = mx[1]; }
    __syncthreads();
    float mfin[2];
    mfin[0] = fmaxf(fmaxf(wrm[c], wrm[32 + c]), fmaxf(wrm[64 + c], wrm[96 + c]));
    mfin[1] = fmaxf(fmaxf(wrm[16 + c], wrm[48 + c]), fmaxf(wrm[80 + c], wrm[112 + c]));

    float sum[2] = {0.0f, 0.0f};
    #pragma unroll
    for (int cc = 0; cc < 8; ++cc)
        #pragma unroll
        for (int kt = 0; kt < 2; ++kt)
            #pragma unroll
            for (int qt = 0; qt < 2; ++qt) {
                f32x4 v = acc[cc][kt][qt];
                v[0] = exp2f((v[0] - mfin[qt]) * LOG2E);
                v[1] = exp2f((v[1] - mfin[qt]) * LOG2E);
                v[2] = exp2f((v[2] - mfin[qt]) * LOG2E);
                v[3] = exp2f((v[3] - mfin[qt]) * LOG2E);
                acc[cc][kt][qt] = v;
                sum[qt] += (v[0] + v[1]) + (v[2] + v[3]);
            }
    #pragma unroll
    for (int qt = 0; qt < 2; ++qt) {
        sum[qt] += __shfl_xor(sum[qt], 16);
        sum[qt] += __shfl_xor(sum[qt], 32);
    }
    if (g == 0) { wrl[w * 32 + c] = sum[0]; wrl[w * 32 + 16 + c] = sum[1]; }
    __syncthreads();
    float inv[2];
    inv[0] = 1.0f / ((wrl[c] + wrl[32 + c]) + (wrl[64 + c] + wrl[96 + c]));
    inv[1] = 1.0f / ((wrl[16 + c] + wrl[48 + c]) + (wrl[80 + c] + wrl[112 + c]));

    // write probs f32 to global (row = qb*32 + local q) + bf16 P into LDS (local q, swizzled)
    float* Pz = P + ((size_t)z << 20);
    #pragma unroll
    for (int cc = 0; cc < 8; ++cc)
        #pragma unroll
        for (int kt = 0; kt < 2; ++kt)
            #pragma unroll
            for (int qt = 0; qt < 2; ++qt) {
                f32x4 v = acc[cc][kt][qt];
                v[0] *= inv[qt]; v[1] *= inv[qt]; v[2] *= inv[qt]; v[3] *= inv[qt];
                int q = qt * 16 + c;                 // local q within 32-row block
                int k = cc * 128 + w * 32 + kt * 16 + g * 4;
                *(f32x4*)(Pz + (size_t)(qb * 32 + q) * 1024 + k) = v;   // FIX: +qb*32
                short4v ps4;
                ps4[0] = f2bf(v[0]); ps4[1] = f2bf(v[1]);
                ps4[2] = f2bf(v[2]); ps4[3] = f2bf(v[3]);
                *(short4v*)(lds + P_O + q * 2048 + ((k * 2) ^ ((q & 7) << 4))) = ps4;
            }
    __syncthreads();

    // PV: ctx[32q][64d] = P @ V; wave w owns d = w*16 + c; V streamed from global (L2-hot)
    {
        const short* vbase = vt + (size_t)z * 65536 + (size_t)(w * 16 + c) * 1024 + g * 8;
        f32x4 pacc[2] = {};
        short8 vfrag = *(const short8*)vbase;
        for (int kc = 0; kc < 32; ++kc) {
            short8 vnext = {};
            if (kc < 31) vnext = *(const short8*)(vbase + (kc + 1) * 32);
            short8 pa[2];
            #pragma unroll
            for (int qt = 0; qt < 2; ++qt) {
                int q = qt * 16 + c;
                int kbyte = kc * 64 + g * 16;
                pa[qt] = *(const short8*)(lds + P_O + q * 2048 + (kbyte ^ ((q & 7) << 4)));
            }
            pacc[0] = MFMA_BF16(pa[0], vfrag, pacc[0]);
            pacc[1] = MFMA_BF16(pa[1], vfrag, pacc[1]);
            vfrag = vnext;
        }
        #pragma unroll
        for (int qt = 0; qt < 2; ++qt) {
            int s = qb * 32 + qt * 16 + g * 4;
            size_t base = ((size_t)b * 1024 + s) * 1024 + h * 64 + w * 16 + c;
            #pragma unroll
            for (int r = 0; r < 4; ++r)
                ctxb[base + (size_t)r * 1024] = f2bf(pacc[qt][r]);
        }
    }
}

extern "C" void kernel_launch(void* const* d_in, const int* in_sizes, int n_in,
                              void* d_out, int out_size, void* d_ws, size_t ws_size,
                              hipStream_t stream) {
    const float* hs   = (const float*)d_in[0];
    const float* mask = (const float*)d_in[1];
    const float* Wq   = (const float*)d_in[2];
    const float* bq   = (const float*)d_in[3];
    const float* Wk   = (const float*)d_in[4];
    const float* bk   = (const float*)d_in[5];
    const float* Wv   = (const float*)d_in[6];
    const float* bv   = (const float*)d_in[7];
    const float* Wo   = (const float*)d_in[8];
    const float* bo   = (const float*)d_in[9];

    float* out   = (float*)d_out;
    float* probs = out + 4194304;

    char* ws = (char*)d_ws;
    short* qhi  = (short*)(ws);
    short* qlo  = (short*)(ws + (8u << 20));
    short* khi  = (short*)(ws + (16u << 20));
    short* klo  = (short*)(ws + (24u << 20));
    short* vt   = (short*)(ws + (32u << 20));
    short* ctxb = (short*)(ws + (40u << 20));
    short* hsb  = (short*)(ws + (48u << 20));
    short* wcat = (short*)(ws + (56u << 20));   // Wq|Wk|Wv|Wo bf16
    short* wob  = wcat + 3 * (1u << 20);

    dim3 blk(256);

    cvt_bf16_kernel<<<2048, blk, 0, stream>>>(hs, hsb, 524288);
    cvt4_kernel<<<2048, blk, 0, stream>>>(Wq, Wk, Wv, Wo, wcat);

    // fused QKV projection: [4096][1024] @ [3072][1024]^T
    gemm128_kernel<1><<<dim3(24, 32), blk, 0, stream>>>(
        hsb, wcat, nullptr, nullptr, qhi, qlo, khi, klo, vt, bq, bk, bv);

    // fused scores+softmax+PV -> probs + ctx
    attn_fused_kernel<<<dim3(32, 64), blk, 0, stream>>>(qhi, qlo, khi, klo, mask, probs,
                                                        vt, ctxb);

    // out = ctx @ Wo^T + bo
    gemm128_kernel<0><<<dim3(8, 32), blk, 0, stream>>>(
        ctxb, wob, out, bo, nullptr, nullptr, nullptr, nullptr, nullptr,
        nullptr, nullptr, nullptr);
}